// Round 6
// baseline (313.653 us; speedup 1.0000x reference)
//
#include <hip/hip_runtime.h>

#define NDIM 128
#define NBKT 512      // dst buckets for CSR build
#define NWPART 128    // partition workgroups

typedef __attribute__((ext_vector_type(8))) short s8v;   // 8 bf16 in 4 VGPRs
typedef __attribute__((ext_vector_type(4))) float f4v;   // MFMA accumulator

__device__ inline unsigned short f2bf_rne(float x) {
    unsigned u = __float_as_uint(x);
    unsigned r = u + 0x7FFFu + ((u >> 16) & 1u);
    return (unsigned short)(r >> 16);
}
__device__ inline float bf2f(unsigned short b) {
    return __uint_as_float(((unsigned)b) << 16);
}

// ---------------- per-node attention projections: s_k = h.Wa_k[0:128], d_k = h.Wa_k[128:256]
__global__ void k_proj(const float* __restrict__ h,
                       const float* __restrict__ Wa1,
                       const float* __restrict__ Wa2,
                       const float* __restrict__ Wa3,
                       float* __restrict__ proj, int N)
{
    int lane = threadIdx.x & 63;
    int wid  = blockIdx.x * (blockDim.x >> 6) + (threadIdx.x >> 6);
    int nw   = gridDim.x * (blockDim.x >> 6);
    float w1s0 = Wa1[lane], w1s1 = Wa1[64 + lane], w1d0 = Wa1[128 + lane], w1d1 = Wa1[192 + lane];
    float w2s0 = Wa2[lane], w2s1 = Wa2[64 + lane], w2d0 = Wa2[128 + lane], w2d1 = Wa2[192 + lane];
    float w3s0 = Wa3[lane], w3s1 = Wa3[64 + lane], w3d0 = Wa3[128 + lane], w3d1 = Wa3[192 + lane];
    for (int n = wid; n < N; n += nw) {
        float h0 = h[(size_t)n * NDIM + lane];
        float h1 = h[(size_t)n * NDIM + 64 + lane];
        float s1 = h0 * w1s0 + h1 * w1s1;
        float s2 = h0 * w2s0 + h1 * w2s1;
        float s3 = h0 * w3s0 + h1 * w3s1;
        float d1 = h0 * w1d0 + h1 * w1d1;
        float d2 = h0 * w2d0 + h1 * w2d1;
        float d3 = h0 * w3d0 + h1 * w3d1;
#pragma unroll
        for (int m = 1; m < 64; m <<= 1) {
            s1 += __shfl_xor(s1, m);
            s2 += __shfl_xor(s2, m);
            s3 += __shfl_xor(s3, m);
            d1 += __shfl_xor(d1, m);
            d2 += __shfl_xor(d2, m);
            d3 += __shfl_xor(d3, m);
        }
        if (lane == 0) {
            *(float4*)(proj + (size_t)n * 8)     = make_float4(s1, s2, s3, 0.f);
            *(float4*)(proj + (size_t)n * 8 + 4) = make_float4(d1, d2, d3, 0.f);
        }
    }
}

// ---------------- partition pass 1: per-(wg,bucket) histogram (LDS atomics only)
__global__ __launch_bounds__(256) void k_part1(const int* __restrict__ dst,
                                               int* __restrict__ hist, int E, int npb)
{
    __shared__ int lh[NBKT];
    int w = blockIdx.x, NW = gridDim.x;
    for (int i = threadIdx.x; i < NBKT; i += 256) lh[i] = 0;
    __syncthreads();
    int per = (E + NW - 1) / NW;
    int e0 = w * per, e1 = min(E, e0 + per);
    for (int e = e0 + threadIdx.x; e < e1; e += 256)
        atomicAdd(&lh[dst[e] / npb], 1);
    __syncthreads();
    for (int b = threadIdx.x; b < NBKT; b += 256)
        hist[b * NW + w] = lh[b];
}

// ---------------- partition scan: per-(bucket,wg) slice offsets + bucket bases
__global__ __launch_bounds__(NBKT) void k_pscan(int* __restrict__ hist,
                                                int* __restrict__ bbase, int NW, int E)
{
    int b = threadIdx.x;
    int tot = 0;
    for (int w = 0; w < NW; ++w) tot += hist[b * NW + w];
    __shared__ int s[NBKT];
    s[b] = tot;
    __syncthreads();
    for (int d = 1; d < NBKT; d <<= 1) {
        int t = (b >= d) ? s[b - d] : 0;
        __syncthreads();
        s[b] += t;
        __syncthreads();
    }
    int base = s[b] - tot;   // exclusive
    bbase[b] = base;
    if (b == NBKT - 1) bbase[NBKT] = E;
    int run = base;
    for (int w = 0; w < NW; ++w) {
        int v = hist[b * NW + w];
        hist[b * NW + w] = run;
        run += v;
    }
}

// ---------------- partition pass 2: scatter packed (src<<7|ldst) into bucket-grouped ebuf
__global__ __launch_bounds__(256) void k_part2(const int* __restrict__ src,
                                               const int* __restrict__ dst,
                                               const int* __restrict__ hist,
                                               unsigned* __restrict__ ebuf, int E, int npb)
{
    __shared__ int cur[NBKT];
    int w = blockIdx.x, NW = gridDim.x;
    for (int i = threadIdx.x; i < NBKT; i += 256) cur[i] = hist[i * NW + w];
    __syncthreads();
    int per = (E + NW - 1) / NW;
    int e0 = w * per, e1 = min(E, e0 + per);
    for (int e = e0 + threadIdx.x; e < e1; e += 256) {
        int d = dst[e], b = d / npb;
        int pos = atomicAdd(&cur[b], 1);
        ebuf[pos] = ((unsigned)src[e] << 7) | (unsigned)(d - b * npb);
    }
}

// ---------------- per-bucket degree count (replaces global-atomic k_hist)
__global__ __launch_bounds__(256) void k_cnt(const unsigned* __restrict__ ebuf,
                                             const int* __restrict__ bbase,
                                             int* __restrict__ cnt, int N, int npb)
{
    __shared__ int lc[128];
    int b = blockIdx.x;
    for (int i = threadIdx.x; i < 128; i += 256) lc[i] = 0;
    __syncthreads();
    int e0 = bbase[b], e1 = bbase[b + 1];
    for (int e = e0 + threadIdx.x; e < e1; e += 256)
        atomicAdd(&lc[ebuf[e] & 127], 1);
    __syncthreads();
    int n0 = b * npb;
    for (int i = threadIdx.x; i < npb; i += 256)
        if (n0 + i < N) cnt[n0 + i] = lc[i];
}

// ---------------- hierarchical exclusive scan (chunk 512)
__global__ void k_scan1(const int* __restrict__ cnt, int* __restrict__ offs,
                        int* __restrict__ bsums, int N)
{
    __shared__ int s[512];
    int i = blockIdx.x * 512 + threadIdx.x;
    int v = (i < N) ? cnt[i] : 0;
    s[threadIdx.x] = v;
    __syncthreads();
    for (int d = 1; d < 512; d <<= 1) {
        int t = (threadIdx.x >= d) ? s[threadIdx.x - d] : 0;
        __syncthreads();
        s[threadIdx.x] += t;
        __syncthreads();
    }
    if (i < N) offs[i] = s[threadIdx.x] - v;
    if (threadIdx.x == 511) bsums[blockIdx.x] = s[511];
}

__global__ void k_scan2(int* __restrict__ bsums, int nb)
{
    __shared__ int s[128];
    int t = threadIdx.x;
    int v = (t < nb) ? bsums[t] : 0;
    s[t] = v;
    __syncthreads();
    for (int d = 1; d < 128; d <<= 1) {
        int u = (t >= d) ? s[t - d] : 0;
        __syncthreads();
        s[t] += u;
        __syncthreads();
    }
    if (t < nb) bsums[t] = s[t] - v;  // exclusive
}

__global__ void k_scan3(int* __restrict__ offs, const int* __restrict__ bsums, int N, int E)
{
    int i = blockIdx.x * 512 + threadIdx.x;
    if (i < N) offs[i] += bsums[blockIdx.x];
    if (i == 0) offs[N] = E;
}

// ---------------- per-bucket CSR scatter: LDS cursors, contiguous per-bucket perm window
__global__ __launch_bounds__(256) void k_perm(const unsigned* __restrict__ ebuf,
                                              const int* __restrict__ bbase,
                                              const int* __restrict__ offs,
                                              int* __restrict__ perm, int N, int npb)
{
    __shared__ int lcur[128];
    int b = blockIdx.x;
    int n0 = b * npb;
    for (int i = threadIdx.x; i < npb; i += 256)
        lcur[i] = (n0 + i < N) ? offs[n0 + i] : 0;
    __syncthreads();
    int e0 = bbase[b], e1 = bbase[b + 1];
    for (int e = e0 + threadIdx.x; e < e1; e += 256) {
        unsigned r = ebuf[e];
        int pos = atomicAdd(&lcur[r & 127], 1);
        perm[pos] = (int)(r >> 7);
    }
}

// ---------------- per-dst-node aggregation, 16-lane group per node (4 nodes/wave)
__global__ __launch_bounds__(256) void k_aggr(const unsigned short* __restrict__ msgb,
                                              const float* __restrict__ proj,
                                              const int* __restrict__ offs,
                                              const int* __restrict__ perm,
                                              const float* __restrict__ ba1,
                                              const float* __restrict__ ba2,
                                              const float* __restrict__ ba3,
                                              float* __restrict__ hneigh, int N)
{
    int tid  = threadIdx.x;
    int lane = tid & 63;
    int l    = lane & 15;          // lane within group
    int g    = lane >> 4;          // group 0..3
    int wvid = blockIdx.x * (blockDim.x >> 6) + (tid >> 6);
    int n    = wvid * 4 + g;       // node owned by this group
    bool alive = (n < N);

    int o0 = 0, o1 = 0;
    float dd1 = 0.f, dd2 = 0.f, dd3 = 0.f;
    if (alive) {
        o0 = offs[n];
        o1 = offs[n + 1];
        dd1 = proj[(size_t)n * 8 + 4];
        dd2 = proj[(size_t)n * 8 + 5];
        dd3 = proj[(size_t)n * 8 + 6];
    }
    int deg = o1 - o0;
    float b1 = ba1[0], b2 = ba2[0], b3 = ba3[0];

    // ---- pass 1: denominators; cache chunk-0 (<=16 edges) numerators + src in regs
    int   m0 = min(deg, 16);
    int   sc = 0;
    float a1c = 0.f, a2c = 0.f, a3c = 0.f;
    if (l < m0) {
        sc = perm[o0 + l];
        float4 sp = *(const float4*)(proj + (size_t)sc * 8);
        a1c = __expf(fmaxf(sp.x + dd1 + b1, 0.f));
        a2c = __expf(fmaxf(sp.y + dd2 + b2, 0.f));
        a3c = __expf(fmaxf(sp.z + dd3 + b3, 0.f));
    }
    float s1 = a1c, s2 = a2c, s3 = a3c;
    for (int i = o0 + 16 + l; i < o1; i += 16) {
        int s = perm[i];
        float4 sp = *(const float4*)(proj + (size_t)s * 8);
        s1 += __expf(fmaxf(sp.x + dd1 + b1, 0.f));
        s2 += __expf(fmaxf(sp.y + dd2 + b2, 0.f));
        s3 += __expf(fmaxf(sp.z + dd3 + b3, 0.f));
    }
#pragma unroll
    for (int m = 1; m < 16; m <<= 1) {   // group-local reduce
        s1 += __shfl_xor(s1, m);
        s2 += __shfl_xor(s2, m);
        s3 += __shfl_xor(s3, m);
    }
    float r1 = 1.f / s1, r2 = 1.f / s2, r3 = 1.f / s3;

    // ---- pass 2: weighted message sum; lane l covers columns l*8..l*8+7
    float acc[8] = {};
    int gbase = g << 4;
    {
        float wv = (a1c * r1 + a2c * r2 + a3c * r3) * (1.f / 3.f);
        for (int j = 0; j < m0; ++j) {
            int   s = __shfl(sc, gbase + j);
            float w = __shfl(wv, gbase + j);
            s8v v = *(const s8v*)(msgb + (size_t)s * NDIM + l * 8);
#pragma unroll
            for (int k = 0; k < 8; ++k)
                acc[k] += w * bf2f((unsigned short)v[k]);
        }
    }
    for (int base = o0 + 16; base < o1; base += 16) {
        int m  = min(16, o1 - base);
        int sv = 0;
        float wv = 0.f;
        if (l < m) {
            sv = perm[base + l];
            float4 sp = *(const float4*)(proj + (size_t)sv * 8);
            float a1 = __expf(fmaxf(sp.x + dd1 + b1, 0.f));
            float a2 = __expf(fmaxf(sp.y + dd2 + b2, 0.f));
            float a3 = __expf(fmaxf(sp.z + dd3 + b3, 0.f));
            wv = (a1 * r1 + a2 * r2 + a3 * r3) * (1.f / 3.f);
        }
        for (int j = 0; j < m; ++j) {
            int   s = __shfl(sv, gbase + j);
            float w = __shfl(wv, gbase + j);
            s8v v = *(const s8v*)(msgb + (size_t)s * NDIM + l * 8);
#pragma unroll
            for (int k = 0; k < 8; ++k)
                acc[k] += w * bf2f((unsigned short)v[k]);
        }
    }
    if (alive) {
        float inv = (deg > 0) ? 1.f / (float)deg : 0.f;
        float* op = hneigh + (size_t)n * NDIM + l * 8;
        *(float4*)(op)     = make_float4(acc[0] * inv, acc[1] * inv, acc[2] * inv, acc[3] * inv);
        *(float4*)(op + 4) = make_float4(acc[4] * inv, acc[5] * inv, acc[6] * inv, acc[7] * inv);
    }
}

// ---------------- weight convert: W[k][c] fp32 -> transposed bf16 hi/lo planes Wt[c][k]
__global__ void k_cvt_w(const float* __restrict__ w0, const float* __restrict__ w1,
                        const float* __restrict__ w2, const float* __restrict__ w3,
                        const float* __restrict__ w4, const float* __restrict__ w5,
                        unsigned short* __restrict__ out)
{
    const float* srcs[6] = {w0, w1, w2, w3, w4, w5};
    const float* W = srcs[blockIdx.y];
    int idx = blockIdx.x * 256 + threadIdx.x;   // = c*128 + k
    int c = idx >> 7, k = idx & 127;
    float x = W[k * 128 + c];
    unsigned xb = __float_as_uint(x);
    float hf = __uint_as_float(xb & 0xFFFF0000u);
    float rr = x - hf;                           // exact residual
    unsigned short hi = (unsigned short)(xb >> 16);
    unsigned short lo = (unsigned short)(__float_as_uint(rr) >> 16);
    unsigned short* ob = out + (size_t)blockIdx.y * 32768;
    ob[idx] = hi;
    ob[16384 + idx] = lo;
}

// ---------------- split-bf16 MFMA GEMM: out[N,128] = act(A@W (+A2@W2) + bias), K=128/pass
__global__ __launch_bounds__(512) void k_mfma(const float* __restrict__ A,
                                              const float* __restrict__ A2,
                                              const unsigned short* __restrict__ wt,
                                              const unsigned short* __restrict__ wt2,
                                              const float* __restrict__ bias,
                                              float* __restrict__ out,
                                              int N, int doRelu, int outBf16)
{
    __shared__ unsigned short Ws[2 * 128 * 128];   // 64 KB: hi plane, lo plane
    int tid  = threadIdx.x;
    int lane = tid & 63;
    int wid  = tid >> 6;
    int ln   = lane & 15;
    int g    = lane >> 4;
    int row0 = blockIdx.x * 128 + wid * 16;
    int rA   = min(row0 + ln, N - 1);

    f4v acc[8] = {};
    int npass = (A2 != nullptr) ? 2 : 1;
    for (int pass = 0; pass < npass; ++pass) {
        const float* Ap = pass ? A2 : A;
        const unsigned short* wp = pass ? wt2 : wt;
        if (pass) __syncthreads();   // all waves done reading Ws of pass 0
        // stage W hi/lo planes (4096 x short8 chunks, coalesced reads, swizzled writes)
#pragma unroll
        for (int i = 0; i < 8; ++i) {
            int c     = tid + 512 * i;
            int plane = c >> 11;
            int cc    = c & 2047;
            int col   = cc >> 4;
            int k0    = (cc & 15) << 3;
            s8v v = *(const s8v*)(wp + plane * 16384 + col * 128 + k0);
            int swz = (col * 128 + k0) ^ ((col & 7) << 3);
            *(s8v*)(&Ws[plane * 16384 + swz]) = v;
        }
        __syncthreads();
        const float* arow = Ap + (size_t)rA * 128 + g * 8;
#pragma unroll
        for (int ks = 0; ks < 4; ++ks) {
            // load 8 fp32 of this lane's A fragment; split into bf16 hi + lo
            float4 x0 = *(const float4*)(arow + ks * 32);
            float4 x1 = *(const float4*)(arow + ks * 32 + 4);
            float xs[8] = {x0.x, x0.y, x0.z, x0.w, x1.x, x1.y, x1.z, x1.w};
            s8v ahi, alo;
#pragma unroll
            for (int j = 0; j < 8; ++j) {
                unsigned xb = __float_as_uint(xs[j]);
                float hf = __uint_as_float(xb & 0xFFFF0000u);
                float rr = xs[j] - hf;
                ahi[j] = (short)(xb >> 16);
                alo[j] = (short)(__float_as_uint(rr) >> 16);
            }
#pragma unroll
            for (int ct = 0; ct < 8; ++ct) {
                int swz = ((ct * 16 + ln) * 128 + ks * 32 + g * 8) ^ ((ln & 7) << 3);
                s8v wh = *(const s8v*)(&Ws[swz]);
                s8v wl = *(const s8v*)(&Ws[16384 + swz]);
                acc[ct] = __builtin_amdgcn_mfma_f32_16x16x32_bf16(ahi, wh, acc[ct], 0, 0, 0);
                acc[ct] = __builtin_amdgcn_mfma_f32_16x16x32_bf16(alo, wh, acc[ct], 0, 0, 0);
                acc[ct] = __builtin_amdgcn_mfma_f32_16x16x32_bf16(ahi, wl, acc[ct], 0, 0, 0);
            }
        }
    }
    __syncthreads();   // drain all A reads before (possibly in-place) writes
    // epilogue: D frag is col=lane&15, row=(lane>>4)*4+reg
#pragma unroll
    for (int ct = 0; ct < 8; ++ct) {
        int col = ct * 16 + ln;
        float bv = bias[col];
#pragma unroll
        for (int q = 0; q < 4; ++q) {
            int orow = row0 + g * 4 + q;
            if (orow < N) {
                float o = acc[ct][q] + bv;
                if (doRelu) o = fmaxf(o, 0.f);
                if (outBf16)
                    ((unsigned short*)out)[(size_t)orow * 128 + col] = f2bf_rne(o);
                else
                    out[(size_t)orow * 128 + col] = o;
            }
        }
    }
}

extern "C" void kernel_launch(void* const* d_in, const int* in_sizes, int n_in,
                              void* d_out, int out_size, void* d_ws, size_t ws_size,
                              hipStream_t stream)
{
    const float* h   = (const float*)d_in[0];
    const int*   src = (const int*)d_in[1];
    const int*   dst = (const int*)d_in[2];
    const float* Wm1 = (const float*)d_in[3];
    const float* bm1 = (const float*)d_in[4];
    const float* Wm2 = (const float*)d_in[5];
    const float* bm2 = (const float*)d_in[6];
    const float* Wm3 = (const float*)d_in[7];
    const float* bm3 = (const float*)d_in[8];
    const float* Wa1 = (const float*)d_in[9];
    const float* ba1 = (const float*)d_in[10];
    const float* Wa2 = (const float*)d_in[11];
    const float* ba2 = (const float*)d_in[12];
    const float* Wa3 = (const float*)d_in[13];
    const float* ba3 = (const float*)d_in[14];
    const float* Wc1 = (const float*)d_in[15];
    const float* bc1 = (const float*)d_in[16];
    const float* Wc2 = (const float*)d_in[17];
    const float* bc2 = (const float*)d_in[18];

    const int N = in_sizes[0] / NDIM;
    const int E = in_sizes[1];
    const int npb = (N + NBKT - 1) / NBKT;     // nodes per bucket (<=128)
    float* out = (float*)d_out;

    // workspace layout (wt first for 16B alignment)
    unsigned short* wt = (unsigned short*)d_ws;            // 6 * 32768 ushorts = 384 KB
    float* bufA = (float*)((char*)d_ws + 6 * 32768 * 2);   // N*128
    float* bufB = bufA + (size_t)N * NDIM;                 // N*128
    float* proj = bufB + (size_t)N * NDIM;                 // N*8
    int* cnt    = (int*)(proj + (size_t)N * 8);            // N
    int* offs   = cnt + N;                                 // N+1
    int* bsums  = offs + N + 1;                            // 128
    int* hist   = bsums + 128;                             // NBKT*NWPART
    int* bbase  = hist + NBKT * NWPART;                    // NBKT+1
    unsigned* ebuf = (unsigned*)(bbase + NBKT + 1);        // E
    int* perm   = (int*)(ebuf + E);                        // E

    const unsigned short* wt_m1  = wt;
    const unsigned short* wt_m2  = wt + 1 * 32768;
    const unsigned short* wt_m3  = wt + 2 * 32768;
    const unsigned short* wt_c1a = wt + 3 * 32768;
    const unsigned short* wt_c1b = wt + 4 * 32768;
    const unsigned short* wt_c2  = wt + 5 * 32768;

    k_cvt_w<<<dim3(64, 6), 256, 0, stream>>>(Wm1, Wm2, Wm3, Wc1, Wc1 + 128 * 128, Wc2, wt);
    k_proj<<<256, 256, 0, stream>>>(h, Wa1, Wa2, Wa3, proj, N);

    // ---- bucketed CSR build (no global atomics)
    k_part1<<<NWPART, 256, 0, stream>>>(dst, hist, E, npb);
    k_pscan<<<1, NBKT, 0, stream>>>(hist, bbase, NWPART, E);
    k_part2<<<NWPART, 256, 0, stream>>>(src, dst, hist, ebuf, E, npb);
    k_cnt<<<NBKT, 256, 0, stream>>>(ebuf, bbase, cnt, N, npb);

    int nb = (N + 511) / 512;
    k_scan1<<<nb, 512, 0, stream>>>(cnt, offs, bsums, N);
    k_scan2<<<1, 128, 0, stream>>>(bsums, nb);
    k_scan3<<<nb, 512, 0, stream>>>(offs, bsums, N, E);

    k_perm<<<NBKT, 256, 0, stream>>>(ebuf, bbase, offs, perm, N, npb);

    int gb = (N + 127) / 128;
    // 3-layer message MLP in node domain; layer 3 writes bf16 msg in-place over bufB
    k_mfma<<<gb, 512, 0, stream>>>(h,    nullptr, wt_m1, nullptr, bm1, bufA, N, 1, 0);
    k_mfma<<<gb, 512, 0, stream>>>(bufA, nullptr, wt_m2, nullptr, bm2, bufB, N, 1, 0);
    k_mfma<<<gb, 512, 0, stream>>>(bufB, nullptr, wt_m3, nullptr, bm3, bufB, N, 1, 1);
    unsigned short* msgb = (unsigned short*)bufB;

    // aggregation: one 16-lane group per node; hneigh -> bufA
    int nwaves = (N + 3) / 4;
    int nblk   = (nwaves + 3) / 4;     // 4 waves per 256-thread block
    k_aggr<<<nblk, 256, 0, stream>>>(msgb, proj, offs, perm, ba1, ba2, ba3, bufA, N);

    // out = relu(h@Wc1[:128] + hneigh@Wc1[128:] + bc1) @ Wc2 + bc2
    k_mfma<<<gb, 512, 0, stream>>>(h, bufA, wt_c1a, wt_c1b, bc1, bufB, N, 1, 0);
    k_mfma<<<gb, 512, 0, stream>>>(bufB, nullptr, wt_c2, nullptr, bc2, out, N, 0, 0);
}

// Round 7
// 221.141 us; speedup vs baseline: 1.4183x; 1.4183x over previous
//
#include <hip/hip_runtime.h>

#define NDIM 128
#define NBKT 512      // dst buckets for CSR build
#define NWPART 128    // partition workgroups

typedef __attribute__((ext_vector_type(8))) short s8v;   // 8 bf16 in 4 VGPRs
typedef __attribute__((ext_vector_type(4))) float f4v;   // MFMA accumulator

__device__ inline unsigned short f2bf_rne(float x) {
    unsigned u = __float_as_uint(x);
    unsigned r = u + 0x7FFFu + ((u >> 16) & 1u);
    return (unsigned short)(r >> 16);
}
__device__ inline float bf2f(unsigned short b) {
    return __uint_as_float(((unsigned)b) << 16);
}

// ---------------- per-node attention projections: s_k = h.Wa_k[0:128], d_k = h.Wa_k[128:256]
__global__ void k_proj(const float* __restrict__ h,
                       const float* __restrict__ Wa1,
                       const float* __restrict__ Wa2,
                       const float* __restrict__ Wa3,
                       float* __restrict__ proj, int N)
{
    int lane = threadIdx.x & 63;
    int wid  = blockIdx.x * (blockDim.x >> 6) + (threadIdx.x >> 6);
    int nw   = gridDim.x * (blockDim.x >> 6);
    float w1s0 = Wa1[lane], w1s1 = Wa1[64 + lane], w1d0 = Wa1[128 + lane], w1d1 = Wa1[192 + lane];
    float w2s0 = Wa2[lane], w2s1 = Wa2[64 + lane], w2d0 = Wa2[128 + lane], w2d1 = Wa2[192 + lane];
    float w3s0 = Wa3[lane], w3s1 = Wa3[64 + lane], w3d0 = Wa3[128 + lane], w3d1 = Wa3[192 + lane];
    for (int n = wid; n < N; n += nw) {
        float h0 = h[(size_t)n * NDIM + lane];
        float h1 = h[(size_t)n * NDIM + 64 + lane];
        float s1 = h0 * w1s0 + h1 * w1s1;
        float s2 = h0 * w2s0 + h1 * w2s1;
        float s3 = h0 * w3s0 + h1 * w3s1;
        float d1 = h0 * w1d0 + h1 * w1d1;
        float d2 = h0 * w2d0 + h1 * w2d1;
        float d3 = h0 * w3d0 + h1 * w3d1;
#pragma unroll
        for (int m = 1; m < 64; m <<= 1) {
            s1 += __shfl_xor(s1, m);
            s2 += __shfl_xor(s2, m);
            s3 += __shfl_xor(s3, m);
            d1 += __shfl_xor(d1, m);
            d2 += __shfl_xor(d2, m);
            d3 += __shfl_xor(d3, m);
        }
        if (lane == 0) {
            *(float4*)(proj + (size_t)n * 8)     = make_float4(s1, s2, s3, 0.f);
            *(float4*)(proj + (size_t)n * 8 + 4) = make_float4(d1, d2, d3, 0.f);
        }
    }
}

// ---------------- partition pass 1: per-(wg,bucket) histogram (LDS atomics only)
__global__ __launch_bounds__(256) void k_part1(const int* __restrict__ dst,
                                               int* __restrict__ hist, int E, int npb)
{
    __shared__ int lh[NBKT];
    int w = blockIdx.x, NW = gridDim.x;
    for (int i = threadIdx.x; i < NBKT; i += 256) lh[i] = 0;
    __syncthreads();
    int per = (E + NW - 1) / NW;
    int e0 = w * per, e1 = min(E, e0 + per);
    for (int e = e0 + threadIdx.x; e < e1; e += 256)
        atomicAdd(&lh[dst[e] / npb], 1);
    __syncthreads();
    for (int b = threadIdx.x; b < NBKT; b += 256)
        hist[b * NW + w] = lh[b];
}

// ---------------- partition scan, parallelized:
// a) per-bucket exclusive scan over its NW slices (one block per bucket)
__global__ __launch_bounds__(NWPART) void k_pscan_a(int* __restrict__ hist,
                                                    int* __restrict__ tot)
{
    __shared__ int s[NWPART];
    int b = blockIdx.x, t = threadIdx.x;
    int v = hist[b * NWPART + t];
    s[t] = v;
    __syncthreads();
    for (int d = 1; d < NWPART; d <<= 1) {
        int u = (t >= d) ? s[t - d] : 0;
        __syncthreads();
        s[t] += u;
        __syncthreads();
    }
    hist[b * NWPART + t] = s[t] - v;      // exclusive within bucket
    if (t == NWPART - 1) tot[b] = s[NWPART - 1];
}

// b) exclusive scan of bucket totals -> bucket bases
__global__ __launch_bounds__(NBKT) void k_pscan_b(const int* __restrict__ tot,
                                                  int* __restrict__ bbase, int E)
{
    __shared__ int s[NBKT];
    int b = threadIdx.x;
    int v = tot[b];
    s[b] = v;
    __syncthreads();
    for (int d = 1; d < NBKT; d <<= 1) {
        int u = (b >= d) ? s[b - d] : 0;
        __syncthreads();
        s[b] += u;
        __syncthreads();
    }
    bbase[b] = s[b] - v;
    if (b == NBKT - 1) bbase[NBKT] = E;
}

// c) add bucket base to each slice offset
__global__ __launch_bounds__(NWPART) void k_pscan_c(int* __restrict__ hist,
                                                    const int* __restrict__ bbase)
{
    int b = blockIdx.x;
    hist[b * NWPART + threadIdx.x] += bbase[b];
}

// ---------------- partition pass 2: scatter packed (src<<7|ldst) into bucket-grouped ebuf
__global__ __launch_bounds__(256) void k_part2(const int* __restrict__ src,
                                               const int* __restrict__ dst,
                                               const int* __restrict__ hist,
                                               unsigned* __restrict__ ebuf, int E, int npb)
{
    __shared__ int cur[NBKT];
    int w = blockIdx.x, NW = gridDim.x;
    for (int i = threadIdx.x; i < NBKT; i += 256) cur[i] = hist[i * NW + w];
    __syncthreads();
    int per = (E + NW - 1) / NW;
    int e0 = w * per, e1 = min(E, e0 + per);
    for (int e = e0 + threadIdx.x; e < e1; e += 256) {
        int d = dst[e], b = d / npb;
        int pos = atomicAdd(&cur[b], 1);
        ebuf[pos] = ((unsigned)src[e] << 7) | (unsigned)(d - b * npb);
    }
}

// ---------------- per-bucket degree count (replaces global-atomic k_hist)
__global__ __launch_bounds__(256) void k_cnt(const unsigned* __restrict__ ebuf,
                                             const int* __restrict__ bbase,
                                             int* __restrict__ cnt, int N, int npb)
{
    __shared__ int lc[128];
    int b = blockIdx.x;
    for (int i = threadIdx.x; i < 128; i += 256) lc[i] = 0;
    __syncthreads();
    int e0 = bbase[b], e1 = bbase[b + 1];
    for (int e = e0 + threadIdx.x; e < e1; e += 256)
        atomicAdd(&lc[ebuf[e] & 127], 1);
    __syncthreads();
    int n0 = b * npb;
    for (int i = threadIdx.x; i < npb; i += 256)
        if (n0 + i < N) cnt[n0 + i] = lc[i];
}

// ---------------- hierarchical exclusive scan (chunk 512)
__global__ void k_scan1(const int* __restrict__ cnt, int* __restrict__ offs,
                        int* __restrict__ bsums, int N)
{
    __shared__ int s[512];
    int i = blockIdx.x * 512 + threadIdx.x;
    int v = (i < N) ? cnt[i] : 0;
    s[threadIdx.x] = v;
    __syncthreads();
    for (int d = 1; d < 512; d <<= 1) {
        int t = (threadIdx.x >= d) ? s[threadIdx.x - d] : 0;
        __syncthreads();
        s[threadIdx.x] += t;
        __syncthreads();
    }
    if (i < N) offs[i] = s[threadIdx.x] - v;
    if (threadIdx.x == 511) bsums[blockIdx.x] = s[511];
}

__global__ void k_scan2(int* __restrict__ bsums, int nb)
{
    __shared__ int s[128];
    int t = threadIdx.x;
    int v = (t < nb) ? bsums[t] : 0;
    s[t] = v;
    __syncthreads();
    for (int d = 1; d < 128; d <<= 1) {
        int u = (t >= d) ? s[t - d] : 0;
        __syncthreads();
        s[t] += u;
        __syncthreads();
    }
    if (t < nb) bsums[t] = s[t] - v;  // exclusive
}

__global__ void k_scan3(int* __restrict__ offs, const int* __restrict__ bsums, int N, int E)
{
    int i = blockIdx.x * 512 + threadIdx.x;
    if (i < N) offs[i] += bsums[blockIdx.x];
    if (i == 0) offs[N] = E;
}

// ---------------- per-bucket CSR scatter: LDS cursors, contiguous per-bucket perm window
__global__ __launch_bounds__(256) void k_perm(const unsigned* __restrict__ ebuf,
                                              const int* __restrict__ bbase,
                                              const int* __restrict__ offs,
                                              int* __restrict__ perm, int N, int npb)
{
    __shared__ int lcur[128];
    int b = blockIdx.x;
    int n0 = b * npb;
    for (int i = threadIdx.x; i < npb; i += 256)
        lcur[i] = (n0 + i < N) ? offs[n0 + i] : 0;
    __syncthreads();
    int e0 = bbase[b], e1 = bbase[b + 1];
    for (int e = e0 + threadIdx.x; e < e1; e += 256) {
        unsigned r = ebuf[e];
        int pos = atomicAdd(&lcur[r & 127], 1);
        perm[pos] = (int)(r >> 7);
    }
}

// ---------------- per-dst-node aggregation, 16-lane group per node (4 nodes/wave)
__global__ __launch_bounds__(256) void k_aggr(const unsigned short* __restrict__ msgb,
                                              const float* __restrict__ proj,
                                              const int* __restrict__ offs,
                                              const int* __restrict__ perm,
                                              const float* __restrict__ ba1,
                                              const float* __restrict__ ba2,
                                              const float* __restrict__ ba3,
                                              float* __restrict__ hneigh, int N)
{
    int tid  = threadIdx.x;
    int lane = tid & 63;
    int l    = lane & 15;          // lane within group
    int g    = lane >> 4;          // group 0..3
    int wvid = blockIdx.x * (blockDim.x >> 6) + (tid >> 6);
    int n    = wvid * 4 + g;       // node owned by this group
    bool alive = (n < N);

    int o0 = 0, o1 = 0;
    float dd1 = 0.f, dd2 = 0.f, dd3 = 0.f;
    if (alive) {
        o0 = offs[n];
        o1 = offs[n + 1];
        dd1 = proj[(size_t)n * 8 + 4];
        dd2 = proj[(size_t)n * 8 + 5];
        dd3 = proj[(size_t)n * 8 + 6];
    }
    int deg = o1 - o0;
    float b1 = ba1[0], b2 = ba2[0], b3 = ba3[0];

    // ---- pass 1: denominators; cache chunk-0 (<=16 edges) numerators + src in regs
    int   m0 = min(deg, 16);
    int   sc = 0;
    float a1c = 0.f, a2c = 0.f, a3c = 0.f;
    if (l < m0) {
        sc = perm[o0 + l];
        float4 sp = *(const float4*)(proj + (size_t)sc * 8);
        a1c = __expf(fmaxf(sp.x + dd1 + b1, 0.f));
        a2c = __expf(fmaxf(sp.y + dd2 + b2, 0.f));
        a3c = __expf(fmaxf(sp.z + dd3 + b3, 0.f));
    }
    float s1 = a1c, s2 = a2c, s3 = a3c;
    for (int i = o0 + 16 + l; i < o1; i += 16) {
        int s = perm[i];
        float4 sp = *(const float4*)(proj + (size_t)s * 8);
        s1 += __expf(fmaxf(sp.x + dd1 + b1, 0.f));
        s2 += __expf(fmaxf(sp.y + dd2 + b2, 0.f));
        s3 += __expf(fmaxf(sp.z + dd3 + b3, 0.f));
    }
#pragma unroll
    for (int m = 1; m < 16; m <<= 1) {   // group-local reduce
        s1 += __shfl_xor(s1, m);
        s2 += __shfl_xor(s2, m);
        s3 += __shfl_xor(s3, m);
    }
    float r1 = 1.f / s1, r2 = 1.f / s2, r3 = 1.f / s3;

    // ---- pass 2: weighted message sum; lane l covers columns l*8..l*8+7
    float acc[8] = {};
    int gbase = g << 4;
    {
        float wv = (a1c * r1 + a2c * r2 + a3c * r3) * (1.f / 3.f);
        for (int j = 0; j < m0; ++j) {
            int   s = __shfl(sc, gbase + j);
            float w = __shfl(wv, gbase + j);
            s8v v = *(const s8v*)(msgb + (size_t)s * NDIM + l * 8);
#pragma unroll
            for (int k = 0; k < 8; ++k)
                acc[k] += w * bf2f((unsigned short)v[k]);
        }
    }
    for (int base = o0 + 16; base < o1; base += 16) {
        int m  = min(16, o1 - base);
        int sv = 0;
        float wv = 0.f;
        if (l < m) {
            sv = perm[base + l];
            float4 sp = *(const float4*)(proj + (size_t)sv * 8);
            float a1 = __expf(fmaxf(sp.x + dd1 + b1, 0.f));
            float a2 = __expf(fmaxf(sp.y + dd2 + b2, 0.f));
            float a3 = __expf(fmaxf(sp.z + dd3 + b3, 0.f));
            wv = (a1 * r1 + a2 * r2 + a3 * r3) * (1.f / 3.f);
        }
        for (int j = 0; j < m; ++j) {
            int   s = __shfl(sv, gbase + j);
            float w = __shfl(wv, gbase + j);
            s8v v = *(const s8v*)(msgb + (size_t)s * NDIM + l * 8);
#pragma unroll
            for (int k = 0; k < 8; ++k)
                acc[k] += w * bf2f((unsigned short)v[k]);
        }
    }
    if (alive) {
        float inv = (deg > 0) ? 1.f / (float)deg : 0.f;
        float* op = hneigh + (size_t)n * NDIM + l * 8;
        *(float4*)(op)     = make_float4(acc[0] * inv, acc[1] * inv, acc[2] * inv, acc[3] * inv);
        *(float4*)(op + 4) = make_float4(acc[4] * inv, acc[5] * inv, acc[6] * inv, acc[7] * inv);
    }
}

// ---------------- weight convert: W[k][c] fp32 -> transposed bf16 hi/lo planes Wt[c][k]
__global__ void k_cvt_w(const float* __restrict__ w0, const float* __restrict__ w1,
                        const float* __restrict__ w2, const float* __restrict__ w3,
                        const float* __restrict__ w4, const float* __restrict__ w5,
                        unsigned short* __restrict__ out)
{
    const float* srcs[6] = {w0, w1, w2, w3, w4, w5};
    const float* W = srcs[blockIdx.y];
    int idx = blockIdx.x * 256 + threadIdx.x;   // = c*128 + k
    int c = idx >> 7, k = idx & 127;
    float x = W[k * 128 + c];
    unsigned xb = __float_as_uint(x);
    float hf = __uint_as_float(xb & 0xFFFF0000u);
    float rr = x - hf;                           // exact residual
    unsigned short hi = (unsigned short)(xb >> 16);
    unsigned short lo = (unsigned short)(__float_as_uint(rr) >> 16);
    unsigned short* ob = out + (size_t)blockIdx.y * 32768;
    ob[idx] = hi;
    ob[16384 + idx] = lo;
}

// ---------------- split-bf16 MFMA GEMM: out[N,128] = act(A@W (+A2@W2) + bias), K=128/pass
__global__ __launch_bounds__(512) void k_mfma(const float* __restrict__ A,
                                              const float* __restrict__ A2,
                                              const unsigned short* __restrict__ wt,
                                              const unsigned short* __restrict__ wt2,
                                              const float* __restrict__ bias,
                                              float* __restrict__ out,
                                              int N, int doRelu, int outBf16)
{
    __shared__ unsigned short Ws[2 * 128 * 128];   // 64 KB: hi plane, lo plane
    int tid  = threadIdx.x;
    int lane = tid & 63;
    int wid  = tid >> 6;
    int ln   = lane & 15;
    int g    = lane >> 4;
    int row0 = blockIdx.x * 128 + wid * 16;
    int rA   = min(row0 + ln, N - 1);

    f4v acc[8] = {};
    int npass = (A2 != nullptr) ? 2 : 1;
    for (int pass = 0; pass < npass; ++pass) {
        const float* Ap = pass ? A2 : A;
        const unsigned short* wp = pass ? wt2 : wt;
        if (pass) __syncthreads();   // all waves done reading Ws of pass 0
        // stage W hi/lo planes (4096 x short8 chunks, coalesced reads, swizzled writes)
#pragma unroll
        for (int i = 0; i < 8; ++i) {
            int c     = tid + 512 * i;
            int plane = c >> 11;
            int cc    = c & 2047;
            int col   = cc >> 4;
            int k0    = (cc & 15) << 3;
            s8v v = *(const s8v*)(wp + plane * 16384 + col * 128 + k0);
            int swz = (col * 128 + k0) ^ ((col & 7) << 3);
            *(s8v*)(&Ws[plane * 16384 + swz]) = v;
        }
        __syncthreads();
        const float* arow = Ap + (size_t)rA * 128 + g * 8;
#pragma unroll
        for (int ks = 0; ks < 4; ++ks) {
            // load 8 fp32 of this lane's A fragment; split into bf16 hi + lo
            float4 x0 = *(const float4*)(arow + ks * 32);
            float4 x1 = *(const float4*)(arow + ks * 32 + 4);
            float xs[8] = {x0.x, x0.y, x0.z, x0.w, x1.x, x1.y, x1.z, x1.w};
            s8v ahi, alo;
#pragma unroll
            for (int j = 0; j < 8; ++j) {
                unsigned xb = __float_as_uint(xs[j]);
                float hf = __uint_as_float(xb & 0xFFFF0000u);
                float rr = xs[j] - hf;
                ahi[j] = (short)(xb >> 16);
                alo[j] = (short)(__float_as_uint(rr) >> 16);
            }
#pragma unroll
            for (int ct = 0; ct < 8; ++ct) {
                int swz = ((ct * 16 + ln) * 128 + ks * 32 + g * 8) ^ ((ln & 7) << 3);
                s8v wh = *(const s8v*)(&Ws[swz]);
                s8v wl = *(const s8v*)(&Ws[16384 + swz]);
                acc[ct] = __builtin_amdgcn_mfma_f32_16x16x32_bf16(ahi, wh, acc[ct], 0, 0, 0);
                acc[ct] = __builtin_amdgcn_mfma_f32_16x16x32_bf16(alo, wh, acc[ct], 0, 0, 0);
                acc[ct] = __builtin_amdgcn_mfma_f32_16x16x32_bf16(ahi, wl, acc[ct], 0, 0, 0);
            }
        }
    }
    __syncthreads();   // drain all A reads before (possibly in-place) writes
    // epilogue: D frag is col=lane&15, row=(lane>>4)*4+reg
#pragma unroll
    for (int ct = 0; ct < 8; ++ct) {
        int col = ct * 16 + ln;
        float bv = bias[col];
#pragma unroll
        for (int q = 0; q < 4; ++q) {
            int orow = row0 + g * 4 + q;
            if (orow < N) {
                float o = acc[ct][q] + bv;
                if (doRelu) o = fmaxf(o, 0.f);
                if (outBf16)
                    ((unsigned short*)out)[(size_t)orow * 128 + col] = f2bf_rne(o);
                else
                    out[(size_t)orow * 128 + col] = o;
            }
        }
    }
}

extern "C" void kernel_launch(void* const* d_in, const int* in_sizes, int n_in,
                              void* d_out, int out_size, void* d_ws, size_t ws_size,
                              hipStream_t stream)
{
    const float* h   = (const float*)d_in[0];
    const int*   src = (const int*)d_in[1];
    const int*   dst = (const int*)d_in[2];
    const float* Wm1 = (const float*)d_in[3];
    const float* bm1 = (const float*)d_in[4];
    const float* Wm2 = (const float*)d_in[5];
    const float* bm2 = (const float*)d_in[6];
    const float* Wm3 = (const float*)d_in[7];
    const float* bm3 = (const float*)d_in[8];
    const float* Wa1 = (const float*)d_in[9];
    const float* ba1 = (const float*)d_in[10];
    const float* Wa2 = (const float*)d_in[11];
    const float* ba2 = (const float*)d_in[12];
    const float* Wa3 = (const float*)d_in[13];
    const float* ba3 = (const float*)d_in[14];
    const float* Wc1 = (const float*)d_in[15];
    const float* bc1 = (const float*)d_in[16];
    const float* Wc2 = (const float*)d_in[17];
    const float* bc2 = (const float*)d_in[18];

    const int N = in_sizes[0] / NDIM;
    const int E = in_sizes[1];
    const int npb = (N + NBKT - 1) / NBKT;     // nodes per bucket (<=128)
    float* out = (float*)d_out;

    // workspace layout (wt first for 16B alignment)
    unsigned short* wt = (unsigned short*)d_ws;            // 6 * 32768 ushorts = 384 KB
    float* bufA = (float*)((char*)d_ws + 6 * 32768 * 2);   // N*128
    float* bufB = bufA + (size_t)N * NDIM;                 // N*128
    float* proj = bufB + (size_t)N * NDIM;                 // N*8
    int* cnt    = (int*)(proj + (size_t)N * 8);            // N
    int* offs   = cnt + N;                                 // N+1
    int* bsums  = offs + N + 1;                            // 128
    int* hist   = bsums + 128;                             // NBKT*NWPART
    int* bbase  = hist + NBKT * NWPART;                    // NBKT+1
    int* btot   = bbase + NBKT + 1;                        // NBKT
    unsigned* ebuf = (unsigned*)(btot + NBKT);             // E
    int* perm   = (int*)(ebuf + E);                        // E

    const unsigned short* wt_m1  = wt;
    const unsigned short* wt_m2  = wt + 1 * 32768;
    const unsigned short* wt_m3  = wt + 2 * 32768;
    const unsigned short* wt_c1a = wt + 3 * 32768;
    const unsigned short* wt_c1b = wt + 4 * 32768;
    const unsigned short* wt_c2  = wt + 5 * 32768;

    k_cvt_w<<<dim3(64, 6), 256, 0, stream>>>(Wm1, Wm2, Wm3, Wc1, Wc1 + 128 * 128, Wc2, wt);
    k_proj<<<256, 256, 0, stream>>>(h, Wa1, Wa2, Wa3, proj, N);

    // ---- bucketed CSR build (no global atomics)
    k_part1<<<NWPART, 256, 0, stream>>>(dst, hist, E, npb);
    k_pscan_a<<<NBKT, NWPART, 0, stream>>>(hist, btot);
    k_pscan_b<<<1, NBKT, 0, stream>>>(btot, bbase, E);
    k_pscan_c<<<NBKT, NWPART, 0, stream>>>(hist, bbase);
    k_part2<<<NWPART, 256, 0, stream>>>(src, dst, hist, ebuf, E, npb);
    k_cnt<<<NBKT, 256, 0, stream>>>(ebuf, bbase, cnt, N, npb);

    int nb = (N + 511) / 512;
    k_scan1<<<nb, 512, 0, stream>>>(cnt, offs, bsums, N);
    k_scan2<<<1, 128, 0, stream>>>(bsums, nb);
    k_scan3<<<nb, 512, 0, stream>>>(offs, bsums, N, E);

    k_perm<<<NBKT, 256, 0, stream>>>(ebuf, bbase, offs, perm, N, npb);

    int gb = (N + 127) / 128;
    // 3-layer message MLP in node domain; layer 3 writes bf16 msg in-place over bufB
    k_mfma<<<gb, 512, 0, stream>>>(h,    nullptr, wt_m1, nullptr, bm1, bufA, N, 1, 0);
    k_mfma<<<gb, 512, 0, stream>>>(bufA, nullptr, wt_m2, nullptr, bm2, bufB, N, 1, 0);
    k_mfma<<<gb, 512, 0, stream>>>(bufB, nullptr, wt_m3, nullptr, bm3, bufB, N, 1, 1);
    unsigned short* msgb = (unsigned short*)bufB;

    // aggregation: one 16-lane group per node; hneigh -> bufA
    int nwaves = (N + 3) / 4;
    int nblk   = (nwaves + 3) / 4;     // 4 waves per 256-thread block
    k_aggr<<<nblk, 256, 0, stream>>>(msgb, proj, offs, perm, ba1, ba2, ba3, bufA, N);

    // out = relu(h@Wc1[:128] + hneigh@Wc1[128:] + bc1) @ Wc2 + bc2
    k_mfma<<<gb, 512, 0, stream>>>(h, bufA, wt_c1a, wt_c1b, bc1, bufB, N, 1, 0);
    k_mfma<<<gb, 512, 0, stream>>>(bufB, nullptr, wt_c2, nullptr, bc2, out, N, 0, 0);
}

// Round 8
// 213.114 us; speedup vs baseline: 1.4718x; 1.0377x over previous
//
#include <hip/hip_runtime.h>

#define NDIM 128
#define NBKT 512      // dst buckets for CSR build
#define NWPART 128    // partition workgroups

typedef __attribute__((ext_vector_type(8))) short s8v;   // 8 bf16 in 4 VGPRs
typedef __attribute__((ext_vector_type(4))) float f4v;   // MFMA accumulator

__device__ inline unsigned short f2bf_rne(float x) {
    unsigned u = __float_as_uint(x);
    unsigned r = u + 0x7FFFu + ((u >> 16) & 1u);
    return (unsigned short)(r >> 16);
}
__device__ inline float bf2f(unsigned short b) {
    return __uint_as_float(((unsigned)b) << 16);
}

// ---------------- per-node attention projections, 16-lane group per node
// proj[n] = {s1,s2,s3,_, d1,d2,d3,_} where s_k = h[n].Wa_k[0:128], d_k = h[n].Wa_k[128:256]
__global__ __launch_bounds__(256) void k_proj(const float* __restrict__ h,
                                              const float* __restrict__ Wa1,
                                              const float* __restrict__ Wa2,
                                              const float* __restrict__ Wa3,
                                              float* __restrict__ proj, int N)
{
    int tid = threadIdx.x;
    int l   = tid & 15;                         // lane in group
    int n   = blockIdx.x * 16 + (tid >> 4);     // node for this group
    if (n >= N) return;
    int o = l * 8;
    // per-lane weight slices (registers, L1-broadcast loads)
    float4 w1s0 = *(const float4*)(Wa1 + o),       w1s1 = *(const float4*)(Wa1 + o + 4);
    float4 w1d0 = *(const float4*)(Wa1 + 128 + o), w1d1 = *(const float4*)(Wa1 + 132 + o);
    float4 w2s0 = *(const float4*)(Wa2 + o),       w2s1 = *(const float4*)(Wa2 + o + 4);
    float4 w2d0 = *(const float4*)(Wa2 + 128 + o), w2d1 = *(const float4*)(Wa2 + 132 + o);
    float4 w3s0 = *(const float4*)(Wa3 + o),       w3s1 = *(const float4*)(Wa3 + o + 4);
    float4 w3d0 = *(const float4*)(Wa3 + 128 + o), w3d1 = *(const float4*)(Wa3 + 132 + o);
    float4 x0 = *(const float4*)(h + (size_t)n * NDIM + o);
    float4 x1 = *(const float4*)(h + (size_t)n * NDIM + o + 4);
    float s1 = x0.x*w1s0.x + x0.y*w1s0.y + x0.z*w1s0.z + x0.w*w1s0.w
             + x1.x*w1s1.x + x1.y*w1s1.y + x1.z*w1s1.z + x1.w*w1s1.w;
    float s2 = x0.x*w2s0.x + x0.y*w2s0.y + x0.z*w2s0.z + x0.w*w2s0.w
             + x1.x*w2s1.x + x1.y*w2s1.y + x1.z*w2s1.z + x1.w*w2s1.w;
    float s3 = x0.x*w3s0.x + x0.y*w3s0.y + x0.z*w3s0.z + x0.w*w3s0.w
             + x1.x*w3s1.x + x1.y*w3s1.y + x1.z*w3s1.z + x1.w*w3s1.w;
    float d1 = x0.x*w1d0.x + x0.y*w1d0.y + x0.z*w1d0.z + x0.w*w1d0.w
             + x1.x*w1d1.x + x1.y*w1d1.y + x1.z*w1d1.z + x1.w*w1d1.w;
    float d2 = x0.x*w2d0.x + x0.y*w2d0.y + x0.z*w2d0.z + x0.w*w2d0.w
             + x1.x*w2d1.x + x1.y*w2d1.y + x1.z*w2d1.z + x1.w*w2d1.w;
    float d3 = x0.x*w3d0.x + x0.y*w3d0.y + x0.z*w3d0.z + x0.w*w3d0.w
             + x1.x*w3d1.x + x1.y*w3d1.y + x1.z*w3d1.z + x1.w*w3d1.w;
#pragma unroll
    for (int m = 1; m < 16; m <<= 1) {
        s1 += __shfl_xor(s1, m);
        s2 += __shfl_xor(s2, m);
        s3 += __shfl_xor(s3, m);
        d1 += __shfl_xor(d1, m);
        d2 += __shfl_xor(d2, m);
        d3 += __shfl_xor(d3, m);
    }
    if (l == 0) {
        *(float4*)(proj + (size_t)n * 8)     = make_float4(s1, s2, s3, 0.f);
        *(float4*)(proj + (size_t)n * 8 + 4) = make_float4(d1, d2, d3, 0.f);
    }
}

// ---------------- partition pass 1: per-(wg,bucket) histogram (LDS atomics only)
__global__ __launch_bounds__(256) void k_part1(const int* __restrict__ dst,
                                               int* __restrict__ hist, int E, int npb)
{
    __shared__ int lh[NBKT];
    int w = blockIdx.x, NW = gridDim.x;
    for (int i = threadIdx.x; i < NBKT; i += 256) lh[i] = 0;
    __syncthreads();
    int per = (E + NW - 1) / NW;
    int e0 = w * per, e1 = min(E, e0 + per);
    for (int e = e0 + threadIdx.x; e < e1; e += 256)
        atomicAdd(&lh[dst[e] / npb], 1);
    __syncthreads();
    for (int b = threadIdx.x; b < NBKT; b += 256)
        hist[b * NW + w] = lh[b];
}

// ---------------- partition scan, parallelized
__global__ __launch_bounds__(NWPART) void k_pscan_a(int* __restrict__ hist,
                                                    int* __restrict__ tot)
{
    __shared__ int s[NWPART];
    int b = blockIdx.x, t = threadIdx.x;
    int v = hist[b * NWPART + t];
    s[t] = v;
    __syncthreads();
    for (int d = 1; d < NWPART; d <<= 1) {
        int u = (t >= d) ? s[t - d] : 0;
        __syncthreads();
        s[t] += u;
        __syncthreads();
    }
    hist[b * NWPART + t] = s[t] - v;      // exclusive within bucket
    if (t == NWPART - 1) tot[b] = s[NWPART - 1];
}

__global__ __launch_bounds__(NBKT) void k_pscan_b(const int* __restrict__ tot,
                                                  int* __restrict__ bbase, int E)
{
    __shared__ int s[NBKT];
    int b = threadIdx.x;
    int v = tot[b];
    s[b] = v;
    __syncthreads();
    for (int d = 1; d < NBKT; d <<= 1) {
        int u = (b >= d) ? s[b - d] : 0;
        __syncthreads();
        s[b] += u;
        __syncthreads();
    }
    bbase[b] = s[b] - v;
    if (b == NBKT - 1) bbase[NBKT] = E;
}

__global__ __launch_bounds__(NWPART) void k_pscan_c(int* __restrict__ hist,
                                                    const int* __restrict__ bbase)
{
    int b = blockIdx.x;
    hist[b * NWPART + threadIdx.x] += bbase[b];
}

// ---------------- partition pass 2: scatter packed (src<<7|ldst) into bucket-grouped ebuf
__global__ __launch_bounds__(256) void k_part2(const int* __restrict__ src,
                                               const int* __restrict__ dst,
                                               const int* __restrict__ hist,
                                               unsigned* __restrict__ ebuf, int E, int npb)
{
    __shared__ int cur[NBKT];
    int w = blockIdx.x, NW = gridDim.x;
    for (int i = threadIdx.x; i < NBKT; i += 256) cur[i] = hist[i * NW + w];
    __syncthreads();
    int per = (E + NW - 1) / NW;
    int e0 = w * per, e1 = min(E, e0 + per);
    for (int e = e0 + threadIdx.x; e < e1; e += 256) {
        int d = dst[e], b = d / npb;
        int pos = atomicAdd(&cur[b], 1);
        ebuf[pos] = ((unsigned)src[e] << 7) | (unsigned)(d - b * npb);
    }
}

// ---------------- per-bucket degree count
__global__ __launch_bounds__(256) void k_cnt(const unsigned* __restrict__ ebuf,
                                             const int* __restrict__ bbase,
                                             int* __restrict__ cnt, int N, int npb)
{
    __shared__ int lc[128];
    int b = blockIdx.x;
    for (int i = threadIdx.x; i < 128; i += 256) lc[i] = 0;
    __syncthreads();
    int e0 = bbase[b], e1 = bbase[b + 1];
    for (int e = e0 + threadIdx.x; e < e1; e += 256)
        atomicAdd(&lc[ebuf[e] & 127], 1);
    __syncthreads();
    int n0 = b * npb;
    for (int i = threadIdx.x; i < npb; i += 256)
        if (n0 + i < N) cnt[n0 + i] = lc[i];
}

// ---------------- hierarchical exclusive scan (chunk 512)
__global__ void k_scan1(const int* __restrict__ cnt, int* __restrict__ offs,
                        int* __restrict__ bsums, int N)
{
    __shared__ int s[512];
    int i = blockIdx.x * 512 + threadIdx.x;
    int v = (i < N) ? cnt[i] : 0;
    s[threadIdx.x] = v;
    __syncthreads();
    for (int d = 1; d < 512; d <<= 1) {
        int t = (threadIdx.x >= d) ? s[threadIdx.x - d] : 0;
        __syncthreads();
        s[threadIdx.x] += t;
        __syncthreads();
    }
    if (i < N) offs[i] = s[threadIdx.x] - v;
    if (threadIdx.x == 511) bsums[blockIdx.x] = s[511];
}

__global__ void k_scan2(int* __restrict__ bsums, int nb)
{
    __shared__ int s[128];
    int t = threadIdx.x;
    int v = (t < nb) ? bsums[t] : 0;
    s[t] = v;
    __syncthreads();
    for (int d = 1; d < 128; d <<= 1) {
        int u = (t >= d) ? s[t - d] : 0;
        __syncthreads();
        s[t] += u;
        __syncthreads();
    }
    if (t < nb) bsums[t] = s[t] - v;  // exclusive
}

__global__ void k_scan3(int* __restrict__ offs, const int* __restrict__ bsums, int N, int E)
{
    int i = blockIdx.x * 512 + threadIdx.x;
    if (i < N) offs[i] += bsums[blockIdx.x];
    if (i == 0) offs[N] = E;
}

// ---------------- per-bucket CSR scatter: LDS cursors, contiguous per-bucket perm window
__global__ __launch_bounds__(256) void k_perm(const unsigned* __restrict__ ebuf,
                                              const int* __restrict__ bbase,
                                              const int* __restrict__ offs,
                                              int* __restrict__ perm, int N, int npb)
{
    __shared__ int lcur[128];
    int b = blockIdx.x;
    int n0 = b * npb;
    for (int i = threadIdx.x; i < npb; i += 256)
        lcur[i] = (n0 + i < N) ? offs[n0 + i] : 0;
    __syncthreads();
    int e0 = bbase[b], e1 = bbase[b + 1];
    for (int e = e0 + threadIdx.x; e < e1; e += 256) {
        unsigned r = ebuf[e];
        int pos = atomicAdd(&lcur[r & 127], 1);
        perm[pos] = (int)(r >> 7);
    }
}

// ---------------- per-dst-node aggregation, 16-lane group per node (4 nodes/wave)
// writes h_neigh as bf16
__global__ __launch_bounds__(256) void k_aggr(const unsigned short* __restrict__ msgb,
                                              const float* __restrict__ proj,
                                              const int* __restrict__ offs,
                                              const int* __restrict__ perm,
                                              const float* __restrict__ ba1,
                                              const float* __restrict__ ba2,
                                              const float* __restrict__ ba3,
                                              unsigned short* __restrict__ hneigh, int N)
{
    int tid  = threadIdx.x;
    int lane = tid & 63;
    int l    = lane & 15;          // lane within group
    int g    = lane >> 4;          // group 0..3
    int wvid = blockIdx.x * (blockDim.x >> 6) + (tid >> 6);
    int n    = wvid * 4 + g;       // node owned by this group
    bool alive = (n < N);

    int o0 = 0, o1 = 0;
    float dd1 = 0.f, dd2 = 0.f, dd3 = 0.f;
    if (alive) {
        o0 = offs[n];
        o1 = offs[n + 1];
        dd1 = proj[(size_t)n * 8 + 4];
        dd2 = proj[(size_t)n * 8 + 5];
        dd3 = proj[(size_t)n * 8 + 6];
    }
    int deg = o1 - o0;
    float b1 = ba1[0], b2 = ba2[0], b3 = ba3[0];

    // ---- pass 1: denominators; cache chunk-0 (<=16 edges) numerators + src in regs
    int   m0 = min(deg, 16);
    int   sc = 0;
    float a1c = 0.f, a2c = 0.f, a3c = 0.f;
    if (l < m0) {
        sc = perm[o0 + l];
        float4 sp = *(const float4*)(proj + (size_t)sc * 8);
        a1c = __expf(fmaxf(sp.x + dd1 + b1, 0.f));
        a2c = __expf(fmaxf(sp.y + dd2 + b2, 0.f));
        a3c = __expf(fmaxf(sp.z + dd3 + b3, 0.f));
    }
    float s1 = a1c, s2 = a2c, s3 = a3c;
    for (int i = o0 + 16 + l; i < o1; i += 16) {
        int s = perm[i];
        float4 sp = *(const float4*)(proj + (size_t)s * 8);
        s1 += __expf(fmaxf(sp.x + dd1 + b1, 0.f));
        s2 += __expf(fmaxf(sp.y + dd2 + b2, 0.f));
        s3 += __expf(fmaxf(sp.z + dd3 + b3, 0.f));
    }
#pragma unroll
    for (int m = 1; m < 16; m <<= 1) {   // group-local reduce
        s1 += __shfl_xor(s1, m);
        s2 += __shfl_xor(s2, m);
        s3 += __shfl_xor(s3, m);
    }
    float r1 = 1.f / s1, r2 = 1.f / s2, r3 = 1.f / s3;

    // ---- pass 2: weighted message sum; lane l covers columns l*8..l*8+7
    float acc[8] = {};
    int gbase = g << 4;
    {
        float wv = (a1c * r1 + a2c * r2 + a3c * r3) * (1.f / 3.f);
        for (int j = 0; j < m0; ++j) {
            int   s = __shfl(sc, gbase + j);
            float w = __shfl(wv, gbase + j);
            s8v v = *(const s8v*)(msgb + (size_t)s * NDIM + l * 8);
#pragma unroll
            for (int k = 0; k < 8; ++k)
                acc[k] += w * bf2f((unsigned short)v[k]);
        }
    }
    for (int base = o0 + 16; base < o1; base += 16) {
        int m  = min(16, o1 - base);
        int sv = 0;
        float wv = 0.f;
        if (l < m) {
            sv = perm[base + l];
            float4 sp = *(const float4*)(proj + (size_t)sv * 8);
            float a1 = __expf(fmaxf(sp.x + dd1 + b1, 0.f));
            float a2 = __expf(fmaxf(sp.y + dd2 + b2, 0.f));
            float a3 = __expf(fmaxf(sp.z + dd3 + b3, 0.f));
            wv = (a1 * r1 + a2 * r2 + a3 * r3) * (1.f / 3.f);
        }
        for (int j = 0; j < m; ++j) {
            int   s = __shfl(sv, gbase + j);
            float w = __shfl(wv, gbase + j);
            s8v v = *(const s8v*)(msgb + (size_t)s * NDIM + l * 8);
#pragma unroll
            for (int k = 0; k < 8; ++k)
                acc[k] += w * bf2f((unsigned short)v[k]);
        }
    }
    if (alive) {
        float inv = (deg > 0) ? 1.f / (float)deg : 0.f;
        s8v hv;
#pragma unroll
        for (int k = 0; k < 8; ++k)
            hv[k] = (short)f2bf_rne(acc[k] * inv);
        *(s8v*)(hneigh + (size_t)n * NDIM + l * 8) = hv;
    }
}

// ---------------- weight convert: W[k][c] fp32 -> transposed bf16 hi/lo planes Wt[c][k]
__global__ void k_cvt_w(const float* __restrict__ w0, const float* __restrict__ w1,
                        const float* __restrict__ w2, const float* __restrict__ w3,
                        const float* __restrict__ w4, const float* __restrict__ w5,
                        unsigned short* __restrict__ out)
{
    const float* srcs[6] = {w0, w1, w2, w3, w4, w5};
    const float* W = srcs[blockIdx.y];
    int idx = blockIdx.x * 256 + threadIdx.x;   // = c*128 + k
    int c = idx >> 7, k = idx & 127;
    float x = W[k * 128 + c];
    unsigned xb = __float_as_uint(x);
    float hf = __uint_as_float(xb & 0xFFFF0000u);
    float rr = x - hf;                           // exact residual
    unsigned short hi = (unsigned short)(xb >> 16);
    unsigned short lo = (unsigned short)(__float_as_uint(rr) >> 16);
    unsigned short* ob = out + (size_t)blockIdx.y * 32768;
    ob[idx] = hi;
    ob[16384 + idx] = lo;
}

// ---------------- split-bf16 MFMA GEMM: out[N,128] = act(A@W (+A2@W2) + bias)
// A operands may be fp32 (split into hi+lo, 3 MFMA) or bf16 (exact, 2 MFMA).
__global__ __launch_bounds__(512) void k_mfma(const void* __restrict__ A,
                                              const void* __restrict__ A2,
                                              const unsigned short* __restrict__ wt,
                                              const unsigned short* __restrict__ wt2,
                                              const float* __restrict__ bias,
                                              void* __restrict__ out,
                                              int N, int doRelu, int outBf16,
                                              int aBf16, int a2Bf16)
{
    __shared__ unsigned short Ws[2 * 128 * 128];   // 64 KB: hi plane, lo plane
    int tid  = threadIdx.x;
    int lane = tid & 63;
    int wid  = tid >> 6;
    int ln   = lane & 15;
    int g    = lane >> 4;
    int row0 = blockIdx.x * 128 + wid * 16;
    int rA   = min(row0 + ln, N - 1);

    f4v acc[8] = {};
    int npass = (A2 != nullptr) ? 2 : 1;
    for (int pass = 0; pass < npass; ++pass) {
        const void* Ap = pass ? A2 : A;
        int isBf = pass ? a2Bf16 : aBf16;
        const unsigned short* wp = pass ? wt2 : wt;
        if (pass) __syncthreads();   // all waves done reading Ws of pass 0
        // stage W hi/lo planes (coalesced reads, swizzled writes)
#pragma unroll
        for (int i = 0; i < 8; ++i) {
            int c     = tid + 512 * i;
            int plane = c >> 11;
            int cc    = c & 2047;
            int col   = cc >> 4;
            int k0    = (cc & 15) << 3;
            s8v v = *(const s8v*)(wp + plane * 16384 + col * 128 + k0);
            int swz = (col * 128 + k0) ^ ((col & 7) << 3);
            *(s8v*)(&Ws[plane * 16384 + swz]) = v;
        }
        __syncthreads();
        if (isBf) {
            const unsigned short* arow = (const unsigned short*)Ap + (size_t)rA * 128 + g * 8;
#pragma unroll
            for (int ks = 0; ks < 4; ++ks) {
                s8v a = *(const s8v*)(arow + ks * 32);
#pragma unroll
                for (int ct = 0; ct < 8; ++ct) {
                    int swz = ((ct * 16 + ln) * 128 + ks * 32 + g * 8) ^ ((ln & 7) << 3);
                    s8v wh = *(const s8v*)(&Ws[swz]);
                    s8v wl = *(const s8v*)(&Ws[16384 + swz]);
                    acc[ct] = __builtin_amdgcn_mfma_f32_16x16x32_bf16(a, wh, acc[ct], 0, 0, 0);
                    acc[ct] = __builtin_amdgcn_mfma_f32_16x16x32_bf16(a, wl, acc[ct], 0, 0, 0);
                }
            }
        } else {
            const float* arow = (const float*)Ap + (size_t)rA * 128 + g * 8;
#pragma unroll
            for (int ks = 0; ks < 4; ++ks) {
                float4 x0 = *(const float4*)(arow + ks * 32);
                float4 x1 = *(const float4*)(arow + ks * 32 + 4);
                float xs[8] = {x0.x, x0.y, x0.z, x0.w, x1.x, x1.y, x1.z, x1.w};
                s8v ahi, alo;
#pragma unroll
                for (int j = 0; j < 8; ++j) {
                    unsigned xb = __float_as_uint(xs[j]);
                    float hf = __uint_as_float(xb & 0xFFFF0000u);
                    float rr = xs[j] - hf;
                    ahi[j] = (short)(xb >> 16);
                    alo[j] = (short)(__float_as_uint(rr) >> 16);
                }
#pragma unroll
                for (int ct = 0; ct < 8; ++ct) {
                    int swz = ((ct * 16 + ln) * 128 + ks * 32 + g * 8) ^ ((ln & 7) << 3);
                    s8v wh = *(const s8v*)(&Ws[swz]);
                    s8v wl = *(const s8v*)(&Ws[16384 + swz]);
                    acc[ct] = __builtin_amdgcn_mfma_f32_16x16x32_bf16(ahi, wh, acc[ct], 0, 0, 0);
                    acc[ct] = __builtin_amdgcn_mfma_f32_16x16x32_bf16(alo, wh, acc[ct], 0, 0, 0);
                    acc[ct] = __builtin_amdgcn_mfma_f32_16x16x32_bf16(ahi, wl, acc[ct], 0, 0, 0);
                }
            }
        }
    }
    __syncthreads();   // drain all A reads before (possibly in-place) writes
    // epilogue: D frag is col=lane&15, row=(lane>>4)*4+reg
#pragma unroll
    for (int ct = 0; ct < 8; ++ct) {
        int col = ct * 16 + ln;
        float bv = bias[col];
#pragma unroll
        for (int q = 0; q < 4; ++q) {
            int orow = row0 + g * 4 + q;
            if (orow < N) {
                float o = acc[ct][q] + bv;
                if (doRelu) o = fmaxf(o, 0.f);
                if (outBf16)
                    ((unsigned short*)out)[(size_t)orow * 128 + col] = f2bf_rne(o);
                else
                    ((float*)out)[(size_t)orow * 128 + col] = o;
            }
        }
    }
}

extern "C" void kernel_launch(void* const* d_in, const int* in_sizes, int n_in,
                              void* d_out, int out_size, void* d_ws, size_t ws_size,
                              hipStream_t stream)
{
    const float* h   = (const float*)d_in[0];
    const int*   src = (const int*)d_in[1];
    const int*   dst = (const int*)d_in[2];
    const float* Wm1 = (const float*)d_in[3];
    const float* bm1 = (const float*)d_in[4];
    const float* Wm2 = (const float*)d_in[5];
    const float* bm2 = (const float*)d_in[6];
    const float* Wm3 = (const float*)d_in[7];
    const float* bm3 = (const float*)d_in[8];
    const float* Wa1 = (const float*)d_in[9];
    const float* ba1 = (const float*)d_in[10];
    const float* Wa2 = (const float*)d_in[11];
    const float* ba2 = (const float*)d_in[12];
    const float* Wa3 = (const float*)d_in[13];
    const float* ba3 = (const float*)d_in[14];
    const float* Wc1 = (const float*)d_in[15];
    const float* bc1 = (const float*)d_in[16];
    const float* Wc2 = (const float*)d_in[17];
    const float* bc2 = (const float*)d_in[18];

    const int N = in_sizes[0] / NDIM;
    const int E = in_sizes[1];
    const int npb = (N + NBKT - 1) / NBKT;     // nodes per bucket (<=128)
    float* out = (float*)d_out;

    // workspace layout (wt first for 16B alignment)
    unsigned short* wt  = (unsigned short*)d_ws;                 // 6 * 32768 ushorts = 384 KB
    unsigned short* mb1 = wt + 6 * 32768;                        // N*128 bf16
    unsigned short* mb2 = mb1 + (size_t)N * NDIM;                // N*128 bf16
    float* proj = (float*)(mb2 + (size_t)N * NDIM);              // N*8
    int* cnt    = (int*)(proj + (size_t)N * 8);                  // N
    int* offs   = cnt + N;                                       // N+1
    int* bsums  = offs + N + 1;                                  // 128
    int* hist   = bsums + 128;                                   // NBKT*NWPART
    int* bbase  = hist + NBKT * NWPART;                          // NBKT+1
    int* btot   = bbase + NBKT + 1;                              // NBKT
    unsigned* ebuf = (unsigned*)(btot + NBKT);                   // E
    int* perm   = (int*)(ebuf + E);                              // E

    const unsigned short* wt_m1  = wt;
    const unsigned short* wt_m2  = wt + 1 * 32768;
    const unsigned short* wt_m3  = wt + 2 * 32768;
    const unsigned short* wt_c1a = wt + 3 * 32768;
    const unsigned short* wt_c1b = wt + 4 * 32768;
    const unsigned short* wt_c2  = wt + 5 * 32768;

    k_cvt_w<<<dim3(64, 6), 256, 0, stream>>>(Wm1, Wm2, Wm3, Wc1, Wc1 + 128 * 128, Wc2, wt);
    k_proj<<<(N + 15) / 16, 256, 0, stream>>>(h, Wa1, Wa2, Wa3, proj, N);

    // ---- bucketed CSR build (no global atomics)
    k_part1<<<NWPART, 256, 0, stream>>>(dst, hist, E, npb);
    k_pscan_a<<<NBKT, NWPART, 0, stream>>>(hist, btot);
    k_pscan_b<<<1, NBKT, 0, stream>>>(btot, bbase, E);
    k_pscan_c<<<NBKT, NWPART, 0, stream>>>(hist, bbase);
    k_part2<<<NWPART, 256, 0, stream>>>(src, dst, hist, ebuf, E, npb);
    k_cnt<<<NBKT, 256, 0, stream>>>(ebuf, bbase, cnt, N, npb);

    int nb = (N + 511) / 512;
    k_scan1<<<nb, 512, 0, stream>>>(cnt, offs, bsums, N);
    k_scan2<<<1, 128, 0, stream>>>(bsums, nb);
    k_scan3<<<nb, 512, 0, stream>>>(offs, bsums, N, E);

    k_perm<<<NBKT, 256, 0, stream>>>(ebuf, bbase, offs, perm, N, npb);

    int gb = (N + 127) / 128;
    // 3-layer message MLP, bf16 activations: h(fp32)->mb1->mb2->mb2(in-place msg)
    k_mfma<<<gb, 512, 0, stream>>>(h,   nullptr, wt_m1, nullptr, bm1, mb1, N, 1, 1, 0, 0);
    k_mfma<<<gb, 512, 0, stream>>>(mb1, nullptr, wt_m2, nullptr, bm2, mb2, N, 1, 1, 1, 0);
    k_mfma<<<gb, 512, 0, stream>>>(mb2, nullptr, wt_m3, nullptr, bm3, mb2, N, 1, 1, 1, 0);

    // aggregation: one 16-lane group per node; h_neigh (bf16) -> mb1
    int nwaves = (N + 3) / 4;
    int nblk   = (nwaves + 3) / 4;     // 4 waves per 256-thread block
    k_aggr<<<nblk, 256, 0, stream>>>(mb2, proj, offs, perm, ba1, ba2, ba3, mb1, N);

    // out = relu(h@Wc1[:128] + hneigh@Wc1[128:] + bc1) @ Wc2 + bc2
    k_mfma<<<gb, 512, 0, stream>>>(h,   mb1, wt_c1a, wt_c1b, bc1, mb2, N, 1, 1, 0, 1);
    k_mfma<<<gb, 512, 0, stream>>>(mb2, nullptr, wt_c2, nullptr, bc2, out, N, 0, 0, 1, 0);
}

// Round 9
// 206.211 us; speedup vs baseline: 1.5210x; 1.0335x over previous
//
#include <hip/hip_runtime.h>

#define NDIM 128
#define NBKT 512      // dst buckets for CSR build
#define NWPART 128    // partition workgroups

typedef __attribute__((ext_vector_type(8))) short s8v;   // 8 bf16 in 4 VGPRs
typedef __attribute__((ext_vector_type(4))) float f4v;   // MFMA accumulator

__device__ inline unsigned short f2bf_rne(float x) {
    unsigned u = __float_as_uint(x);
    unsigned r = u + 0x7FFFu + ((u >> 16) & 1u);
    return (unsigned short)(r >> 16);
}
__device__ inline float bf2f(unsigned short b) {
    return __uint_as_float(((unsigned)b) << 16);
}

// ---------------- per-node attention projections, 16-lane group per node
__global__ __launch_bounds__(256) void k_proj(const float* __restrict__ h,
                                              const float* __restrict__ Wa1,
                                              const float* __restrict__ Wa2,
                                              const float* __restrict__ Wa3,
                                              float* __restrict__ proj, int N)
{
    int tid = threadIdx.x;
    int l   = tid & 15;                         // lane in group
    int n   = blockIdx.x * 16 + (tid >> 4);     // node for this group
    if (n >= N) return;
    int o = l * 8;
    float4 w1s0 = *(const float4*)(Wa1 + o),       w1s1 = *(const float4*)(Wa1 + o + 4);
    float4 w1d0 = *(const float4*)(Wa1 + 128 + o), w1d1 = *(const float4*)(Wa1 + 132 + o);
    float4 w2s0 = *(const float4*)(Wa2 + o),       w2s1 = *(const float4*)(Wa2 + o + 4);
    float4 w2d0 = *(const float4*)(Wa2 + 128 + o), w2d1 = *(const float4*)(Wa2 + 132 + o);
    float4 w3s0 = *(const float4*)(Wa3 + o),       w3s1 = *(const float4*)(Wa3 + o + 4);
    float4 w3d0 = *(const float4*)(Wa3 + 128 + o), w3d1 = *(const float4*)(Wa3 + 132 + o);
    float4 x0 = *(const float4*)(h + (size_t)n * NDIM + o);
    float4 x1 = *(const float4*)(h + (size_t)n * NDIM + o + 4);
    float s1 = x0.x*w1s0.x + x0.y*w1s0.y + x0.z*w1s0.z + x0.w*w1s0.w
             + x1.x*w1s1.x + x1.y*w1s1.y + x1.z*w1s1.z + x1.w*w1s1.w;
    float s2 = x0.x*w2s0.x + x0.y*w2s0.y + x0.z*w2s0.z + x0.w*w2s0.w
             + x1.x*w2s1.x + x1.y*w2s1.y + x1.z*w2s1.z + x1.w*w2s1.w;
    float s3 = x0.x*w3s0.x + x0.y*w3s0.y + x0.z*w3s0.z + x0.w*w3s0.w
             + x1.x*w3s1.x + x1.y*w3s1.y + x1.z*w3s1.z + x1.w*w3s1.w;
    float d1 = x0.x*w1d0.x + x0.y*w1d0.y + x0.z*w1d0.z + x0.w*w1d0.w
             + x1.x*w1d1.x + x1.y*w1d1.y + x1.z*w1d1.z + x1.w*w1d1.w;
    float d2 = x0.x*w2d0.x + x0.y*w2d0.y + x0.z*w2d0.z + x0.w*w2d0.w
             + x1.x*w2d1.x + x1.y*w2d1.y + x1.z*w2d1.z + x1.w*w2d1.w;
    float d3 = x0.x*w3d0.x + x0.y*w3d0.y + x0.z*w3d0.z + x0.w*w3d0.w
             + x1.x*w3d1.x + x1.y*w3d1.y + x1.z*w3d1.z + x1.w*w3d1.w;
#pragma unroll
    for (int m = 1; m < 16; m <<= 1) {
        s1 += __shfl_xor(s1, m);
        s2 += __shfl_xor(s2, m);
        s3 += __shfl_xor(s3, m);
        d1 += __shfl_xor(d1, m);
        d2 += __shfl_xor(d2, m);
        d3 += __shfl_xor(d3, m);
    }
    if (l == 0) {
        *(float4*)(proj + (size_t)n * 8)     = make_float4(s1, s2, s3, 0.f);
        *(float4*)(proj + (size_t)n * 8 + 4) = make_float4(d1, d2, d3, 0.f);
    }
}

// ---------------- partition pass 1: per-(wg,bucket) histogram (LDS atomics only)
__global__ __launch_bounds__(256) void k_part1(const int* __restrict__ dst,
                                               int* __restrict__ hist, int E, int npb)
{
    __shared__ int lh[NBKT];
    int w = blockIdx.x, NW = gridDim.x;
    for (int i = threadIdx.x; i < NBKT; i += 256) lh[i] = 0;
    __syncthreads();
    int per = (E + NW - 1) / NW;
    int e0 = w * per, e1 = min(E, e0 + per);
    for (int e = e0 + threadIdx.x; e < e1; e += 256)
        atomicAdd(&lh[dst[e] / npb], 1);
    __syncthreads();
    for (int b = threadIdx.x; b < NBKT; b += 256)
        hist[b * NW + w] = lh[b];
}

// ---------------- partition scan, parallelized
__global__ __launch_bounds__(NWPART) void k_pscan_a(int* __restrict__ hist,
                                                    int* __restrict__ tot)
{
    __shared__ int s[NWPART];
    int b = blockIdx.x, t = threadIdx.x;
    int v = hist[b * NWPART + t];
    s[t] = v;
    __syncthreads();
    for (int d = 1; d < NWPART; d <<= 1) {
        int u = (t >= d) ? s[t - d] : 0;
        __syncthreads();
        s[t] += u;
        __syncthreads();
    }
    hist[b * NWPART + t] = s[t] - v;      // exclusive within bucket
    if (t == NWPART - 1) tot[b] = s[NWPART - 1];
}

__global__ __launch_bounds__(NBKT) void k_pscan_b(const int* __restrict__ tot,
                                                  int* __restrict__ bbase, int E)
{
    __shared__ int s[NBKT];
    int b = threadIdx.x;
    int v = tot[b];
    s[b] = v;
    __syncthreads();
    for (int d = 1; d < NBKT; d <<= 1) {
        int u = (b >= d) ? s[b - d] : 0;
        __syncthreads();
        s[b] += u;
        __syncthreads();
    }
    bbase[b] = s[b] - v;
    if (b == NBKT - 1) bbase[NBKT] = E;
}

// ---------------- partition pass 2 (+ bucket-base add): scatter packed records
__global__ __launch_bounds__(256) void k_part2(const int* __restrict__ src,
                                               const int* __restrict__ dst,
                                               const int* __restrict__ hist,
                                               const int* __restrict__ bbase,
                                               unsigned* __restrict__ ebuf, int E, int npb)
{
    __shared__ int cur[NBKT];
    int w = blockIdx.x, NW = gridDim.x;
    for (int i = threadIdx.x; i < NBKT; i += 256)
        cur[i] = hist[i * NW + w] + bbase[i];
    __syncthreads();
    int per = (E + NW - 1) / NW;
    int e0 = w * per, e1 = min(E, e0 + per);
    for (int e = e0 + threadIdx.x; e < e1; e += 256) {
        int d = dst[e], b = d / npb;
        int pos = atomicAdd(&cur[b], 1);
        ebuf[pos] = ((unsigned)src[e] << 7) | (unsigned)(d - b * npb);
    }
}

// ---------------- fused per-bucket: degree count -> LDS scan -> offs -> perm scatter
__global__ __launch_bounds__(256) void k_bucket(const unsigned* __restrict__ ebuf,
                                                const int* __restrict__ bbase,
                                                int* __restrict__ offs,
                                                int* __restrict__ perm,
                                                int N, int npb, int E)
{
    __shared__ int lc[128];   // degree count, then cursor
    __shared__ int ls[128];   // scan workspace
    int b   = blockIdx.x;
    int tid = threadIdx.x;
    for (int i = tid; i < 128; i += 256) lc[i] = 0;
    __syncthreads();
    int e0 = bbase[b], e1 = bbase[b + 1];
    for (int e = e0 + tid; e < e1; e += 256)
        atomicAdd(&lc[ebuf[e] & 127], 1);
    __syncthreads();
    if (tid < 128) ls[tid] = lc[tid];
    __syncthreads();
    for (int d = 1; d < 128; d <<= 1) {
        int u = (tid < 128 && tid >= d) ? ls[tid - d] : 0;
        __syncthreads();
        if (tid < 128) ls[tid] += u;
        __syncthreads();
    }
    int n0 = b * npb;
    if (tid < 128) {
        int excl = ls[tid] - lc[tid] + e0;    // exclusive scan + bucket base
        if (tid < npb && n0 + tid < N) offs[n0 + tid] = excl;
        lc[tid] = excl;                        // cursor
    }
    if (b == 0 && tid == 0) offs[N] = E;
    __syncthreads();
    for (int e = e0 + tid; e < e1; e += 256) {
        unsigned r = ebuf[e];
        int pos = atomicAdd(&lc[r & 127], 1);
        perm[pos] = (int)(r >> 7);
    }
}

// ---------------- per-dst-node aggregation, 16-lane group per node (4 nodes/wave)
__global__ __launch_bounds__(256) void k_aggr(const unsigned short* __restrict__ msgb,
                                              const float* __restrict__ proj,
                                              const int* __restrict__ offs,
                                              const int* __restrict__ perm,
                                              const float* __restrict__ ba1,
                                              const float* __restrict__ ba2,
                                              const float* __restrict__ ba3,
                                              unsigned short* __restrict__ hneigh, int N)
{
    int tid  = threadIdx.x;
    int lane = tid & 63;
    int l    = lane & 15;          // lane within group
    int g    = lane >> 4;          // group 0..3
    int wvid = blockIdx.x * (blockDim.x >> 6) + (tid >> 6);
    int n    = wvid * 4 + g;       // node owned by this group
    bool alive = (n < N);

    int o0 = 0, o1 = 0;
    float dd1 = 0.f, dd2 = 0.f, dd3 = 0.f;
    if (alive) {
        o0 = offs[n];
        o1 = offs[n + 1];
        dd1 = proj[(size_t)n * 8 + 4];
        dd2 = proj[(size_t)n * 8 + 5];
        dd3 = proj[(size_t)n * 8 + 6];
    }
    int deg = o1 - o0;
    float b1 = ba1[0], b2 = ba2[0], b3 = ba3[0];

    // ---- pass 1: denominators; cache chunk-0 (<=16 edges) numerators + src in regs
    int   m0 = min(deg, 16);
    int   sc = 0;
    float a1c = 0.f, a2c = 0.f, a3c = 0.f;
    if (l < m0) {
        sc = perm[o0 + l];
        float4 sp = *(const float4*)(proj + (size_t)sc * 8);
        a1c = __expf(fmaxf(sp.x + dd1 + b1, 0.f));
        a2c = __expf(fmaxf(sp.y + dd2 + b2, 0.f));
        a3c = __expf(fmaxf(sp.z + dd3 + b3, 0.f));
    }
    float s1 = a1c, s2 = a2c, s3 = a3c;
    for (int i = o0 + 16 + l; i < o1; i += 16) {
        int s = perm[i];
        float4 sp = *(const float4*)(proj + (size_t)s * 8);
        s1 += __expf(fmaxf(sp.x + dd1 + b1, 0.f));
        s2 += __expf(fmaxf(sp.y + dd2 + b2, 0.f));
        s3 += __expf(fmaxf(sp.z + dd3 + b3, 0.f));
    }
#pragma unroll
    for (int m = 1; m < 16; m <<= 1) {   // group-local reduce
        s1 += __shfl_xor(s1, m);
        s2 += __shfl_xor(s2, m);
        s3 += __shfl_xor(s3, m);
    }
    float r1 = 1.f / s1, r2 = 1.f / s2, r3 = 1.f / s3;

    // ---- pass 2: weighted message sum; lane l covers columns l*8..l*8+7
    float acc[8] = {};
    int gbase = g << 4;
    {
        float wv = (a1c * r1 + a2c * r2 + a3c * r3) * (1.f / 3.f);
        for (int j = 0; j < m0; ++j) {
            int   s = __shfl(sc, gbase + j);
            float w = __shfl(wv, gbase + j);
            s8v v = *(const s8v*)(msgb + (size_t)s * NDIM + l * 8);
#pragma unroll
            for (int k = 0; k < 8; ++k)
                acc[k] += w * bf2f((unsigned short)v[k]);
        }
    }
    for (int base = o0 + 16; base < o1; base += 16) {
        int m  = min(16, o1 - base);
        int sv = 0;
        float wv = 0.f;
        if (l < m) {
            sv = perm[base + l];
            float4 sp = *(const float4*)(proj + (size_t)sv * 8);
            float a1 = __expf(fmaxf(sp.x + dd1 + b1, 0.f));
            float a2 = __expf(fmaxf(sp.y + dd2 + b2, 0.f));
            float a3 = __expf(fmaxf(sp.z + dd3 + b3, 0.f));
            wv = (a1 * r1 + a2 * r2 + a3 * r3) * (1.f / 3.f);
        }
        for (int j = 0; j < m; ++j) {
            int   s = __shfl(sv, gbase + j);
            float w = __shfl(wv, gbase + j);
            s8v v = *(const s8v*)(msgb + (size_t)s * NDIM + l * 8);
#pragma unroll
            for (int k = 0; k < 8; ++k)
                acc[k] += w * bf2f((unsigned short)v[k]);
        }
    }
    if (alive) {
        float inv = (deg > 0) ? 1.f / (float)deg : 0.f;
        s8v hv;
#pragma unroll
        for (int k = 0; k < 8; ++k)
            hv[k] = (short)f2bf_rne(acc[k] * inv);
        *(s8v*)(hneigh + (size_t)n * NDIM + l * 8) = hv;
    }
}

// ---------------- weight convert: W[k][c] fp32 -> transposed bf16 hi/lo planes Wt[c][k]
__global__ void k_cvt_w(const float* __restrict__ w0, const float* __restrict__ w1,
                        const float* __restrict__ w2, const float* __restrict__ w3,
                        const float* __restrict__ w4, const float* __restrict__ w5,
                        unsigned short* __restrict__ out)
{
    const float* srcs[6] = {w0, w1, w2, w3, w4, w5};
    const float* W = srcs[blockIdx.y];
    int idx = blockIdx.x * 256 + threadIdx.x;   // = c*128 + k
    int c = idx >> 7, k = idx & 127;
    float x = W[k * 128 + c];
    unsigned xb = __float_as_uint(x);
    float hf = __uint_as_float(xb & 0xFFFF0000u);
    float rr = x - hf;                           // exact residual
    unsigned short hi = (unsigned short)(xb >> 16);
    unsigned short lo = (unsigned short)(__float_as_uint(rr) >> 16);
    unsigned short* ob = out + (size_t)blockIdx.y * 32768;
    ob[idx] = hi;
    ob[16384 + idx] = lo;
}

// ---------------- split-bf16 MFMA GEMM: out[N,128] = act(A@W (+A2@W2) + bias)
// BM=64, 8 waves as 2 row-groups x 4 col-groups; each wave computes a 32x32 tile.
// ds_read:MFMA = 1:2 (vs 1:1 for the row-wave layout). W hi/lo in LDS, XOR swizzle.
__global__ __launch_bounds__(512) void k_mfma(const void* __restrict__ A,
                                              const void* __restrict__ A2,
                                              const unsigned short* __restrict__ wt,
                                              const unsigned short* __restrict__ wt2,
                                              const float* __restrict__ bias,
                                              void* __restrict__ out,
                                              int N, int doRelu, int outBf16,
                                              int aBf16, int a2Bf16)
{
    __shared__ unsigned short Ws[2 * 128 * 128];   // 64 KB: hi plane, lo plane
    int tid  = threadIdx.x;
    int lane = tid & 63;
    int wid  = tid >> 6;        // 0..7
    int rw   = wid >> 2;        // 0..1 row-group
    int cw   = wid & 3;         // 0..3 col-group
    int ln   = lane & 15;
    int g    = lane >> 4;
    int row0 = blockIdx.x * 64 + rw * 32;

    f4v acc[2][2] = {};
    int npass = (A2 != nullptr) ? 2 : 1;
    for (int pass = 0; pass < npass; ++pass) {
        const void* Ap = pass ? A2 : A;
        int isBf = pass ? a2Bf16 : aBf16;
        const unsigned short* wp = pass ? wt2 : wt;
        if (pass) __syncthreads();   // all waves done reading Ws of pass 0
        // stage W hi/lo planes (coalesced reads, swizzled writes)
#pragma unroll
        for (int i = 0; i < 8; ++i) {
            int c     = tid + 512 * i;
            int plane = c >> 11;
            int cc    = c & 2047;
            int col   = cc >> 4;
            int k0    = (cc & 15) << 3;
            s8v v = *(const s8v*)(wp + plane * 16384 + col * 128 + k0);
            int swz = (col * 128 + k0) ^ ((col & 7) << 3);
            *(s8v*)(&Ws[plane * 16384 + swz]) = v;
        }
        __syncthreads();
        if (isBf) {
            const unsigned short* abase = (const unsigned short*)Ap;
#pragma unroll
            for (int ks = 0; ks < 4; ++ks) {
                s8v a[2];
#pragma unroll
                for (int fr = 0; fr < 2; ++fr) {
                    int rA = min(row0 + fr * 16 + ln, N - 1);
                    a[fr] = *(const s8v*)(abase + (size_t)rA * 128 + ks * 32 + g * 8);
                }
#pragma unroll
                for (int ct2 = 0; ct2 < 2; ++ct2) {
                    int ct = cw * 2 + ct2;
                    int swz = ((ct * 16 + ln) * 128 + ks * 32 + g * 8) ^ ((ln & 7) << 3);
                    s8v wh = *(const s8v*)(&Ws[swz]);
                    s8v wl = *(const s8v*)(&Ws[16384 + swz]);
#pragma unroll
                    for (int fr = 0; fr < 2; ++fr) {
                        acc[fr][ct2] = __builtin_amdgcn_mfma_f32_16x16x32_bf16(a[fr], wh, acc[fr][ct2], 0, 0, 0);
                        acc[fr][ct2] = __builtin_amdgcn_mfma_f32_16x16x32_bf16(a[fr], wl, acc[fr][ct2], 0, 0, 0);
                    }
                }
            }
        } else {
            const float* abase = (const float*)Ap;
#pragma unroll
            for (int ks = 0; ks < 4; ++ks) {
                s8v ahi[2], alo[2];
#pragma unroll
                for (int fr = 0; fr < 2; ++fr) {
                    int rA = min(row0 + fr * 16 + ln, N - 1);
                    const float* arow = abase + (size_t)rA * 128 + ks * 32 + g * 8;
                    float4 x0 = *(const float4*)(arow);
                    float4 x1 = *(const float4*)(arow + 4);
                    float xs[8] = {x0.x, x0.y, x0.z, x0.w, x1.x, x1.y, x1.z, x1.w};
#pragma unroll
                    for (int j = 0; j < 8; ++j) {
                        unsigned xb = __float_as_uint(xs[j]);
                        float hf = __uint_as_float(xb & 0xFFFF0000u);
                        float rr = xs[j] - hf;
                        ahi[fr][j] = (short)(xb >> 16);
                        alo[fr][j] = (short)(__float_as_uint(rr) >> 16);
                    }
                }
#pragma unroll
                for (int ct2 = 0; ct2 < 2; ++ct2) {
                    int ct = cw * 2 + ct2;
                    int swz = ((ct * 16 + ln) * 128 + ks * 32 + g * 8) ^ ((ln & 7) << 3);
                    s8v wh = *(const s8v*)(&Ws[swz]);
                    s8v wl = *(const s8v*)(&Ws[16384 + swz]);
#pragma unroll
                    for (int fr = 0; fr < 2; ++fr) {
                        acc[fr][ct2] = __builtin_amdgcn_mfma_f32_16x16x32_bf16(ahi[fr], wh, acc[fr][ct2], 0, 0, 0);
                        acc[fr][ct2] = __builtin_amdgcn_mfma_f32_16x16x32_bf16(alo[fr], wh, acc[fr][ct2], 0, 0, 0);
                        acc[fr][ct2] = __builtin_amdgcn_mfma_f32_16x16x32_bf16(ahi[fr], wl, acc[fr][ct2], 0, 0, 0);
                    }
                }
            }
        }
    }
    __syncthreads();   // drain all A reads before (possibly in-place) writes
    // epilogue: D frag is col=lane&15, row=(lane>>4)*4+reg
#pragma unroll
    for (int ct2 = 0; ct2 < 2; ++ct2) {
        int col = (cw * 2 + ct2) * 16 + ln;
        float bv = bias[col];
#pragma unroll
        for (int fr = 0; fr < 2; ++fr) {
#pragma unroll
            for (int q = 0; q < 4; ++q) {
                int orow = row0 + fr * 16 + g * 4 + q;
                if (orow < N) {
                    float o = acc[fr][ct2][q] + bv;
                    if (doRelu) o = fmaxf(o, 0.f);
                    if (outBf16)
                        ((unsigned short*)out)[(size_t)orow * 128 + col] = f2bf_rne(o);
                    else
                        ((float*)out)[(size_t)orow * 128 + col] = o;
                }
            }
        }
    }
}

extern "C" void kernel_launch(void* const* d_in, const int* in_sizes, int n_in,
                              void* d_out, int out_size, void* d_ws, size_t ws_size,
                              hipStream_t stream)
{
    const float* h   = (const float*)d_in[0];
    const int*   src = (const int*)d_in[1];
    const int*   dst = (const int*)d_in[2];
    const float* Wm1 = (const float*)d_in[3];
    const float* bm1 = (const float*)d_in[4];
    const float* Wm2 = (const float*)d_in[5];
    const float* bm2 = (const float*)d_in[6];
    const float* Wm3 = (const float*)d_in[7];
    const float* bm3 = (const float*)d_in[8];
    const float* Wa1 = (const float*)d_in[9];
    const float* ba1 = (const float*)d_in[10];
    const float* Wa2 = (const float*)d_in[11];
    const float* ba2 = (const float*)d_in[12];
    const float* Wa3 = (const float*)d_in[13];
    const float* ba3 = (const float*)d_in[14];
    const float* Wc1 = (const float*)d_in[15];
    const float* bc1 = (const float*)d_in[16];
    const float* Wc2 = (const float*)d_in[17];
    const float* bc2 = (const float*)d_in[18];

    const int N = in_sizes[0] / NDIM;
    const int E = in_sizes[1];
    const int npb = (N + NBKT - 1) / NBKT;     // nodes per bucket (<=128)
    float* out = (float*)d_out;

    // workspace layout (wt first for 16B alignment)
    unsigned short* wt  = (unsigned short*)d_ws;                 // 6 * 32768 ushorts = 384 KB
    unsigned short* mb1 = wt + 6 * 32768;                        // N*128 bf16
    unsigned short* mb2 = mb1 + (size_t)N * NDIM;                // N*128 bf16
    float* proj = (float*)(mb2 + (size_t)N * NDIM);              // N*8
    int* offs   = (int*)(proj + (size_t)N * 8);                  // N+1
    int* hist   = offs + N + 1;                                  // NBKT*NWPART
    int* bbase  = hist + NBKT * NWPART;                          // NBKT+1
    int* btot   = bbase + NBKT + 1;                              // NBKT
    unsigned* ebuf = (unsigned*)(btot + NBKT);                   // E
    int* perm   = (int*)(ebuf + E);                              // E

    const unsigned short* wt_m1  = wt;
    const unsigned short* wt_m2  = wt + 1 * 32768;
    const unsigned short* wt_m3  = wt + 2 * 32768;
    const unsigned short* wt_c1a = wt + 3 * 32768;
    const unsigned short* wt_c1b = wt + 4 * 32768;
    const unsigned short* wt_c2  = wt + 5 * 32768;

    k_cvt_w<<<dim3(64, 6), 256, 0, stream>>>(Wm1, Wm2, Wm3, Wc1, Wc1 + 128 * 128, Wc2, wt);
    k_proj<<<(N + 15) / 16, 256, 0, stream>>>(h, Wa1, Wa2, Wa3, proj, N);

    // ---- bucketed CSR build (no global atomics), fused scan/perm
    k_part1<<<NWPART, 256, 0, stream>>>(dst, hist, E, npb);
    k_pscan_a<<<NBKT, NWPART, 0, stream>>>(hist, btot);
    k_pscan_b<<<1, NBKT, 0, stream>>>(btot, bbase, E);
    k_part2<<<NWPART, 256, 0, stream>>>(src, dst, hist, bbase, ebuf, E, npb);
    k_bucket<<<NBKT, 256, 0, stream>>>(ebuf, bbase, offs, perm, N, npb, E);

    int gb = (N + 63) / 64;
    // 3-layer message MLP, bf16 activations: h(fp32)->mb1->mb2->mb2(in-place msg)
    k_mfma<<<gb, 512, 0, stream>>>(h,   nullptr, wt_m1, nullptr, bm1, mb1, N, 1, 1, 0, 0);
    k_mfma<<<gb, 512, 0, stream>>>(mb1, nullptr, wt_m2, nullptr, bm2, mb2, N, 1, 1, 1, 0);
    k_mfma<<<gb, 512, 0, stream>>>(mb2, nullptr, wt_m3, nullptr, bm3, mb2, N, 1, 1, 1, 0);

    // aggregation: one 16-lane group per node; h_neigh (bf16) -> mb1
    int nwaves = (N + 3) / 4;
    int nblk   = (nwaves + 3) / 4;     // 4 waves per 256-thread block
    k_aggr<<<nblk, 256, 0, stream>>>(mb2, proj, offs, perm, ba1, ba2, ba3, mb1, N);

    // out = relu(h@Wc1[:128] + hneigh@Wc1[128:] + bc1) @ Wc2 + bc2
    k_mfma<<<gb, 512, 0, stream>>>(h,   mb1, wt_c1a, wt_c1b, bc1, mb2, N, 1, 1, 0, 1);
    k_mfma<<<gb, 512, 0, stream>>>(mb2, nullptr, wt_c2, nullptr, bc2, out, N, 0, 0, 1, 0);
}

// Round 10
// 164.249 us; speedup vs baseline: 1.9096x; 1.2555x over previous
//
#include <hip/hip_runtime.h>

#define NDIM 128
#define NBKT 512      // dst buckets for CSR build
#define NWPART 128    // partition workgroups

typedef __attribute__((ext_vector_type(8))) short s8v;   // 8 bf16 in 4 VGPRs
typedef __attribute__((ext_vector_type(4))) float f4v;   // MFMA accumulator

__device__ inline unsigned short f2bf_rne(float x) {
    unsigned u = __float_as_uint(x);
    unsigned r = u + 0x7FFFu + ((u >> 16) & 1u);
    return (unsigned short)(r >> 16);
}
__device__ inline float bf2f(unsigned short b) {
    return __uint_as_float(((unsigned)b) << 16);
}

// ---------------- per-node attention projections, 16-lane group per node
__global__ __launch_bounds__(256) void k_proj(const float* __restrict__ h,
                                              const float* __restrict__ Wa1,
                                              const float* __restrict__ Wa2,
                                              const float* __restrict__ Wa3,
                                              float* __restrict__ proj, int N)
{
    int tid = threadIdx.x;
    int l   = tid & 15;
    int n   = blockIdx.x * 16 + (tid >> 4);
    if (n >= N) return;
    int o = l * 8;
    float4 w1s0 = *(const float4*)(Wa1 + o),       w1s1 = *(const float4*)(Wa1 + o + 4);
    float4 w1d0 = *(const float4*)(Wa1 + 128 + o), w1d1 = *(const float4*)(Wa1 + 132 + o);
    float4 w2s0 = *(const float4*)(Wa2 + o),       w2s1 = *(const float4*)(Wa2 + o + 4);
    float4 w2d0 = *(const float4*)(Wa2 + 128 + o), w2d1 = *(const float4*)(Wa2 + 132 + o);
    float4 w3s0 = *(const float4*)(Wa3 + o),       w3s1 = *(const float4*)(Wa3 + o + 4);
    float4 w3d0 = *(const float4*)(Wa3 + 128 + o), w3d1 = *(const float4*)(Wa3 + 132 + o);
    float4 x0 = *(const float4*)(h + (size_t)n * NDIM + o);
    float4 x1 = *(const float4*)(h + (size_t)n * NDIM + o + 4);
    float s1 = x0.x*w1s0.x + x0.y*w1s0.y + x0.z*w1s0.z + x0.w*w1s0.w
             + x1.x*w1s1.x + x1.y*w1s1.y + x1.z*w1s1.z + x1.w*w1s1.w;
    float s2 = x0.x*w2s0.x + x0.y*w2s0.y + x0.z*w2s0.z + x0.w*w2s0.w
             + x1.x*w2s1.x + x1.y*w2s1.y + x1.z*w2s1.z + x1.w*w2s1.w;
    float s3 = x0.x*w3s0.x + x0.y*w3s0.y + x0.z*w3s0.z + x0.w*w3s0.w
             + x1.x*w3s1.x + x1.y*w3s1.y + x1.z*w3s1.z + x1.w*w3s1.w;
    float d1 = x0.x*w1d0.x + x0.y*w1d0.y + x0.z*w1d0.z + x0.w*w1d0.w
             + x1.x*w1d1.x + x1.y*w1d1.y + x1.z*w1d1.z + x1.w*w1d1.w;
    float d2 = x0.x*w2d0.x + x0.y*w2d0.y + x0.z*w2d0.z + x0.w*w2d0.w
             + x1.x*w2d1.x + x1.y*w2d1.y + x1.z*w2d1.z + x1.w*w2d1.w;
    float d3 = x0.x*w3d0.x + x0.y*w3d0.y + x0.z*w3d0.z + x0.w*w3d0.w
             + x1.x*w3d1.x + x1.y*w3d1.y + x1.z*w3d1.z + x1.w*w3d1.w;
#pragma unroll
    for (int m = 1; m < 16; m <<= 1) {
        s1 += __shfl_xor(s1, m);
        s2 += __shfl_xor(s2, m);
        s3 += __shfl_xor(s3, m);
        d1 += __shfl_xor(d1, m);
        d2 += __shfl_xor(d2, m);
        d3 += __shfl_xor(d3, m);
    }
    if (l == 0) {
        *(float4*)(proj + (size_t)n * 8)     = make_float4(s1, s2, s3, 0.f);
        *(float4*)(proj + (size_t)n * 8 + 4) = make_float4(d1, d2, d3, 0.f);
    }
}

// ---------------- partition pass 1: per-(wg,bucket) histogram (LDS atomics only)
__global__ __launch_bounds__(256) void k_part1(const int* __restrict__ dst,
                                               int* __restrict__ hist, int E, int npb)
{
    __shared__ int lh[NBKT];
    int w = blockIdx.x, NW = gridDim.x;
    for (int i = threadIdx.x; i < NBKT; i += 256) lh[i] = 0;
    __syncthreads();
    int per = (E + NW - 1) / NW;
    int e0 = w * per, e1 = min(E, e0 + per);
    for (int e = e0 + threadIdx.x; e < e1; e += 256)
        atomicAdd(&lh[dst[e] / npb], 1);
    __syncthreads();
    for (int b = threadIdx.x; b < NBKT; b += 256)
        hist[b * NW + w] = lh[b];
}

// ---------------- partition scan, parallelized
__global__ __launch_bounds__(NWPART) void k_pscan_a(int* __restrict__ hist,
                                                    int* __restrict__ tot)
{
    __shared__ int s[NWPART];
    int b = blockIdx.x, t = threadIdx.x;
    int v = hist[b * NWPART + t];
    s[t] = v;
    __syncthreads();
    for (int d = 1; d < NWPART; d <<= 1) {
        int u = (t >= d) ? s[t - d] : 0;
        __syncthreads();
        s[t] += u;
        __syncthreads();
    }
    hist[b * NWPART + t] = s[t] - v;
    if (t == NWPART - 1) tot[b] = s[NWPART - 1];
}

__global__ __launch_bounds__(NBKT) void k_pscan_b(const int* __restrict__ tot,
                                                  int* __restrict__ bbase, int E)
{
    __shared__ int s[NBKT];
    int b = threadIdx.x;
    int v = tot[b];
    s[b] = v;
    __syncthreads();
    for (int d = 1; d < NBKT; d <<= 1) {
        int u = (b >= d) ? s[b - d] : 0;
        __syncthreads();
        s[b] += u;
        __syncthreads();
    }
    bbase[b] = s[b] - v;
    if (b == NBKT - 1) bbase[NBKT] = E;
}

// ---------------- partition pass 2 (+ bucket-base add): scatter packed records
__global__ __launch_bounds__(256) void k_part2(const int* __restrict__ src,
                                               const int* __restrict__ dst,
                                               const int* __restrict__ hist,
                                               const int* __restrict__ bbase,
                                               unsigned* __restrict__ ebuf, int E, int npb)
{
    __shared__ int cur[NBKT];
    int w = blockIdx.x, NW = gridDim.x;
    for (int i = threadIdx.x; i < NBKT; i += 256)
        cur[i] = hist[i * NW + w] + bbase[i];
    __syncthreads();
    int per = (E + NW - 1) / NW;
    int e0 = w * per, e1 = min(E, e0 + per);
    for (int e = e0 + threadIdx.x; e < e1; e += 256) {
        int d = dst[e], b = d / npb;
        int pos = atomicAdd(&cur[b], 1);
        ebuf[pos] = ((unsigned)src[e] << 7) | (unsigned)(d - b * npb);
    }
}

// ---------------- fused per-bucket: degree count -> LDS scan -> offs -> perm scatter
__global__ __launch_bounds__(256) void k_bucket(const unsigned* __restrict__ ebuf,
                                                const int* __restrict__ bbase,
                                                int* __restrict__ offs,
                                                int* __restrict__ perm,
                                                int N, int npb, int E)
{
    __shared__ int lc[128];
    __shared__ int ls[128];
    int b   = blockIdx.x;
    int tid = threadIdx.x;
    for (int i = tid; i < 128; i += 256) lc[i] = 0;
    __syncthreads();
    int e0 = bbase[b], e1 = bbase[b + 1];
    for (int e = e0 + tid; e < e1; e += 256)
        atomicAdd(&lc[ebuf[e] & 127], 1);
    __syncthreads();
    if (tid < 128) ls[tid] = lc[tid];
    __syncthreads();
    for (int d = 1; d < 128; d <<= 1) {
        int u = (tid < 128 && tid >= d) ? ls[tid - d] : 0;
        __syncthreads();
        if (tid < 128) ls[tid] += u;
        __syncthreads();
    }
    int n0 = b * npb;
    if (tid < 128) {
        int excl = ls[tid] - lc[tid] + e0;
        if (tid < npb && n0 + tid < N) offs[n0 + tid] = excl;
        lc[tid] = excl;
    }
    if (b == 0 && tid == 0) offs[N] = E;
    __syncthreads();
    for (int e = e0 + tid; e < e1; e += 256) {
        unsigned r = ebuf[e];
        int pos = atomicAdd(&lc[r & 127], 1);
        perm[pos] = (int)(r >> 7);
    }
}

// ---------------- per-dst-node aggregation, 16-lane group per node (4 nodes/wave)
__global__ __launch_bounds__(256) void k_aggr(const unsigned short* __restrict__ msgb,
                                              const float* __restrict__ proj,
                                              const int* __restrict__ offs,
                                              const int* __restrict__ perm,
                                              const float* __restrict__ ba1,
                                              const float* __restrict__ ba2,
                                              const float* __restrict__ ba3,
                                              unsigned short* __restrict__ hneigh, int N)
{
    int tid  = threadIdx.x;
    int lane = tid & 63;
    int l    = lane & 15;
    int g    = lane >> 4;
    int wvid = blockIdx.x * (blockDim.x >> 6) + (tid >> 6);
    int n    = wvid * 4 + g;
    bool alive = (n < N);

    int o0 = 0, o1 = 0;
    float dd1 = 0.f, dd2 = 0.f, dd3 = 0.f;
    if (alive) {
        o0 = offs[n];
        o1 = offs[n + 1];
        dd1 = proj[(size_t)n * 8 + 4];
        dd2 = proj[(size_t)n * 8 + 5];
        dd3 = proj[(size_t)n * 8 + 6];
    }
    int deg = o1 - o0;
    float b1 = ba1[0], b2 = ba2[0], b3 = ba3[0];

    int   m0 = min(deg, 16);
    int   sc = 0;
    float a1c = 0.f, a2c = 0.f, a3c = 0.f;
    if (l < m0) {
        sc = perm[o0 + l];
        float4 sp = *(const float4*)(proj + (size_t)sc * 8);
        a1c = __expf(fmaxf(sp.x + dd1 + b1, 0.f));
        a2c = __expf(fmaxf(sp.y + dd2 + b2, 0.f));
        a3c = __expf(fmaxf(sp.z + dd3 + b3, 0.f));
    }
    float s1 = a1c, s2 = a2c, s3 = a3c;
    for (int i = o0 + 16 + l; i < o1; i += 16) {
        int s = perm[i];
        float4 sp = *(const float4*)(proj + (size_t)s * 8);
        s1 += __expf(fmaxf(sp.x + dd1 + b1, 0.f));
        s2 += __expf(fmaxf(sp.y + dd2 + b2, 0.f));
        s3 += __expf(fmaxf(sp.z + dd3 + b3, 0.f));
    }
#pragma unroll
    for (int m = 1; m < 16; m <<= 1) {
        s1 += __shfl_xor(s1, m);
        s2 += __shfl_xor(s2, m);
        s3 += __shfl_xor(s3, m);
    }
    float r1 = 1.f / s1, r2 = 1.f / s2, r3 = 1.f / s3;

    float acc[8] = {};
    int gbase = g << 4;
    {
        float wv = (a1c * r1 + a2c * r2 + a3c * r3) * (1.f / 3.f);
        for (int j = 0; j < m0; ++j) {
            int   s = __shfl(sc, gbase + j);
            float w = __shfl(wv, gbase + j);
            s8v v = *(const s8v*)(msgb + (size_t)s * NDIM + l * 8);
#pragma unroll
            for (int k = 0; k < 8; ++k)
                acc[k] += w * bf2f((unsigned short)v[k]);
        }
    }
    for (int base = o0 + 16; base < o1; base += 16) {
        int m  = min(16, o1 - base);
        int sv = 0;
        float wv = 0.f;
        if (l < m) {
            sv = perm[base + l];
            float4 sp = *(const float4*)(proj + (size_t)sv * 8);
            float a1 = __expf(fmaxf(sp.x + dd1 + b1, 0.f));
            float a2 = __expf(fmaxf(sp.y + dd2 + b2, 0.f));
            float a3 = __expf(fmaxf(sp.z + dd3 + b3, 0.f));
            wv = (a1 * r1 + a2 * r2 + a3 * r3) * (1.f / 3.f);
        }
        for (int j = 0; j < m; ++j) {
            int   s = __shfl(sv, gbase + j);
            float w = __shfl(wv, gbase + j);
            s8v v = *(const s8v*)(msgb + (size_t)s * NDIM + l * 8);
#pragma unroll
            for (int k = 0; k < 8; ++k)
                acc[k] += w * bf2f((unsigned short)v[k]);
        }
    }
    if (alive) {
        float inv = (deg > 0) ? 1.f / (float)deg : 0.f;
        s8v hv;
#pragma unroll
        for (int k = 0; k < 8; ++k)
            hv[k] = (short)f2bf_rne(acc[k] * inv);
        *(s8v*)(hneigh + (size_t)n * NDIM + l * 8) = hv;
    }
}

// ---------------- weight convert: W[k][c] fp32 -> transposed bf16 hi/lo planes Wt[c][k]
__global__ void k_cvt_w(const float* __restrict__ w0, const float* __restrict__ w1,
                        const float* __restrict__ w2, const float* __restrict__ w3,
                        const float* __restrict__ w4, const float* __restrict__ w5,
                        unsigned short* __restrict__ out)
{
    const float* srcs[6] = {w0, w1, w2, w3, w4, w5};
    const float* W = srcs[blockIdx.y];
    int idx = blockIdx.x * 256 + threadIdx.x;
    int c = idx >> 7, k = idx & 127;
    float x = W[k * 128 + c];
    unsigned xb = __float_as_uint(x);
    float hf = __uint_as_float(xb & 0xFFFF0000u);
    float rr = x - hf;
    unsigned short hi = (unsigned short)(xb >> 16);
    unsigned short lo = (unsigned short)(__float_as_uint(rr) >> 16);
    unsigned short* ob = out + (size_t)blockIdx.y * 32768;
    ob[idx] = hi;
    ob[16384 + idx] = lo;
}

// ======== fused-GEMM building blocks (BM=64, 8 waves = 2 row x 4 col, 32x32/wave) ========
// Ws: 32768 ushorts (hi plane 16384, lo plane 16384), XOR-swizzled. act: 8192 ushorts.

__device__ inline void stage_planes(const unsigned short* __restrict__ wp,
                                    unsigned short* __restrict__ Ws, int tid)
{
#pragma unroll
    for (int i = 0; i < 8; ++i) {
        int c     = tid + 512 * i;
        int plane = c >> 11;
        int cc    = c & 2047;
        int col   = cc >> 4;
        int k0    = (cc & 15) << 3;
        s8v v = *(const s8v*)(wp + plane * 16384 + col * 128 + k0);
        int swz = (col * 128 + k0) ^ ((col & 7) << 3);
        *(s8v*)(&Ws[plane * 16384 + swz]) = v;
    }
}

__device__ inline void mfma_f32_pass(const float* __restrict__ A, int N, int row0,
                                     int ln, int g, int cw,
                                     const unsigned short* __restrict__ Ws,
                                     f4v acc[2][2])
{
#pragma unroll
    for (int ks = 0; ks < 4; ++ks) {
        s8v ahi[2], alo[2];
#pragma unroll
        for (int fr = 0; fr < 2; ++fr) {
            int rA = min(row0 + fr * 16 + ln, N - 1);
            const float* ar = A + (size_t)rA * 128 + ks * 32 + g * 8;
            float4 x0 = *(const float4*)(ar);
            float4 x1 = *(const float4*)(ar + 4);
            float xs[8] = {x0.x, x0.y, x0.z, x0.w, x1.x, x1.y, x1.z, x1.w};
#pragma unroll
            for (int j = 0; j < 8; ++j) {
                unsigned xb = __float_as_uint(xs[j]);
                float hf = __uint_as_float(xb & 0xFFFF0000u);
                float rr = xs[j] - hf;
                ahi[fr][j] = (short)(xb >> 16);
                alo[fr][j] = (short)(__float_as_uint(rr) >> 16);
            }
        }
#pragma unroll
        for (int ct2 = 0; ct2 < 2; ++ct2) {
            int ct = cw * 2 + ct2;
            int swz = ((ct * 16 + ln) * 128 + ks * 32 + g * 8) ^ ((ln & 7) << 3);
            s8v wh = *(const s8v*)(&Ws[swz]);
            s8v wl = *(const s8v*)(&Ws[16384 + swz]);
#pragma unroll
            for (int fr = 0; fr < 2; ++fr) {
                acc[fr][ct2] = __builtin_amdgcn_mfma_f32_16x16x32_bf16(ahi[fr], wh, acc[fr][ct2], 0, 0, 0);
                acc[fr][ct2] = __builtin_amdgcn_mfma_f32_16x16x32_bf16(alo[fr], wh, acc[fr][ct2], 0, 0, 0);
                acc[fr][ct2] = __builtin_amdgcn_mfma_f32_16x16x32_bf16(ahi[fr], wl, acc[fr][ct2], 0, 0, 0);
            }
        }
    }
}

__device__ inline void mfma_bf16g_pass(const unsigned short* __restrict__ A, int N, int row0,
                                       int ln, int g, int cw,
                                       const unsigned short* __restrict__ Ws,
                                       f4v acc[2][2])
{
#pragma unroll
    for (int ks = 0; ks < 4; ++ks) {
        s8v a[2];
#pragma unroll
        for (int fr = 0; fr < 2; ++fr) {
            int rA = min(row0 + fr * 16 + ln, N - 1);
            a[fr] = *(const s8v*)(A + (size_t)rA * 128 + ks * 32 + g * 8);
        }
#pragma unroll
        for (int ct2 = 0; ct2 < 2; ++ct2) {
            int ct = cw * 2 + ct2;
            int swz = ((ct * 16 + ln) * 128 + ks * 32 + g * 8) ^ ((ln & 7) << 3);
            s8v wh = *(const s8v*)(&Ws[swz]);
            s8v wl = *(const s8v*)(&Ws[16384 + swz]);
#pragma unroll
            for (int fr = 0; fr < 2; ++fr) {
                acc[fr][ct2] = __builtin_amdgcn_mfma_f32_16x16x32_bf16(a[fr], wh, acc[fr][ct2], 0, 0, 0);
                acc[fr][ct2] = __builtin_amdgcn_mfma_f32_16x16x32_bf16(a[fr], wl, acc[fr][ct2], 0, 0, 0);
            }
        }
    }
}

__device__ inline void mfma_lds_pass(const unsigned short* __restrict__ act,
                                     int rw, int ln, int g, int cw,
                                     const unsigned short* __restrict__ Ws,
                                     f4v acc[2][2])
{
#pragma unroll
    for (int ks = 0; ks < 4; ++ks) {
        s8v a[2];
#pragma unroll
        for (int fr = 0; fr < 2; ++fr) {
            int rl = rw * 32 + fr * 16 + ln;
            a[fr] = *(const s8v*)(&act[(rl * 128 + ks * 32 + g * 8) ^ ((ln & 7) << 3)]);
        }
#pragma unroll
        for (int ct2 = 0; ct2 < 2; ++ct2) {
            int ct = cw * 2 + ct2;
            int swz = ((ct * 16 + ln) * 128 + ks * 32 + g * 8) ^ ((ln & 7) << 3);
            s8v wh = *(const s8v*)(&Ws[swz]);
            s8v wl = *(const s8v*)(&Ws[16384 + swz]);
#pragma unroll
            for (int fr = 0; fr < 2; ++fr) {
                acc[fr][ct2] = __builtin_amdgcn_mfma_f32_16x16x32_bf16(a[fr], wh, acc[fr][ct2], 0, 0, 0);
                acc[fr][ct2] = __builtin_amdgcn_mfma_f32_16x16x32_bf16(a[fr], wl, acc[fr][ct2], 0, 0, 0);
            }
        }
    }
}

// bias + relu + bf16 round -> swizzled act LDS; zeros acc
__device__ inline void write_act(f4v acc[2][2], const float* __restrict__ bias,
                                 unsigned short* __restrict__ act,
                                 int rw, int cw, int ln, int g)
{
#pragma unroll
    for (int ct2 = 0; ct2 < 2; ++ct2) {
        int col = (cw * 2 + ct2) * 16 + ln;
        float bv = bias[col];
#pragma unroll
        for (int fr = 0; fr < 2; ++fr) {
#pragma unroll
            for (int q = 0; q < 4; ++q) {
                int rl = rw * 32 + fr * 16 + g * 4 + q;
                float o = fmaxf(acc[fr][ct2][q] + bv, 0.f);
                act[(rl * 128 + col) ^ ((rl & 7) << 3)] = f2bf_rne(o);
                acc[fr][ct2][q] = 0.f;
            }
        }
    }
}

// ---------------- fused 3-layer message MLP: h(fp32) -> relu MLP x3 -> msg (bf16 global)
__global__ __launch_bounds__(512) void k_mlp3(const float* __restrict__ h,
                                              const unsigned short* __restrict__ w1,
                                              const unsigned short* __restrict__ w2,
                                              const unsigned short* __restrict__ w3,
                                              const float* __restrict__ b1,
                                              const float* __restrict__ b2,
                                              const float* __restrict__ b3,
                                              unsigned short* __restrict__ msg, int N)
{
    extern __shared__ unsigned short sm[];
    unsigned short* Ws  = sm;           // 32768 ushorts = 64 KB
    unsigned short* act = sm + 32768;   // 8192 ushorts = 16 KB
    int tid  = threadIdx.x;
    int lane = tid & 63;
    int wid  = tid >> 6;
    int rw   = wid >> 2;
    int cw   = wid & 3;
    int ln   = lane & 15;
    int g    = lane >> 4;
    int row0 = blockIdx.x * 64 + rw * 32;

    f4v acc[2][2] = {};
    // layer 1 (fp32 h from global)
    stage_planes(w1, Ws, tid);
    __syncthreads();
    mfma_f32_pass(h, N, row0, ln, g, cw, Ws, acc);
    __syncthreads();
    write_act(acc, b1, act, rw, cw, ln, g);
    __syncthreads();
    // layer 2
    stage_planes(w2, Ws, tid);
    __syncthreads();
    mfma_lds_pass(act, rw, ln, g, cw, Ws, acc);
    __syncthreads();
    write_act(acc, b2, act, rw, cw, ln, g);
    __syncthreads();
    // layer 3
    stage_planes(w3, Ws, tid);
    __syncthreads();
    mfma_lds_pass(act, rw, ln, g, cw, Ws, acc);
    __syncthreads();
    write_act(acc, b3, act, rw, cw, ln, g);
    __syncthreads();
    // coalesced copyout
#pragma unroll
    for (int i = 0; i < 2; ++i) {
        int id  = tid + 512 * i;
        int row = id >> 4;
        int c8  = (id & 15) * 8;
        int grow = blockIdx.x * 64 + row;
        if (grow < N) {
            s8v v = *(const s8v*)(&act[(row * 128 + c8) ^ ((row & 7) << 3)]);
            *(s8v*)(msg + (size_t)grow * 128 + c8) = v;
        }
    }
}

// ---------------- fused head: out = relu(h@Wc1a + hneigh@Wc1b + bc1) @ Wc2 + bc2
__global__ __launch_bounds__(512) void k_head(const float* __restrict__ h,
                                              const unsigned short* __restrict__ hneigh,
                                              const unsigned short* __restrict__ wc1a,
                                              const unsigned short* __restrict__ wc1b,
                                              const unsigned short* __restrict__ wc2,
                                              const float* __restrict__ bc1,
                                              const float* __restrict__ bc2,
                                              float* __restrict__ out, int N)
{
    extern __shared__ unsigned short sm[];
    unsigned short* Ws  = sm;
    unsigned short* act = sm + 32768;
    int tid  = threadIdx.x;
    int lane = tid & 63;
    int wid  = tid >> 6;
    int rw   = wid >> 2;
    int cw   = wid & 3;
    int ln   = lane & 15;
    int g    = lane >> 4;
    int row0 = blockIdx.x * 64 + rw * 32;

    f4v acc[2][2] = {};
    // c1 = relu(h@Wc1a + hneigh@Wc1b + bc1)
    stage_planes(wc1a, Ws, tid);
    __syncthreads();
    mfma_f32_pass(h, N, row0, ln, g, cw, Ws, acc);
    __syncthreads();
    stage_planes(wc1b, Ws, tid);
    __syncthreads();
    mfma_bf16g_pass(hneigh, N, row0, ln, g, cw, Ws, acc);
    __syncthreads();
    write_act(acc, bc1, act, rw, cw, ln, g);
    __syncthreads();
    // c2
    stage_planes(wc2, Ws, tid);
    __syncthreads();
    mfma_lds_pass(act, rw, ln, g, cw, Ws, acc);
    // epilogue: fp32 global store
#pragma unroll
    for (int ct2 = 0; ct2 < 2; ++ct2) {
        int col = (cw * 2 + ct2) * 16 + ln;
        float bv = bc2[col];
#pragma unroll
        for (int fr = 0; fr < 2; ++fr) {
#pragma unroll
            for (int q = 0; q < 4; ++q) {
                int orow = row0 + fr * 16 + g * 4 + q;
                if (orow < N)
                    out[(size_t)orow * 128 + col] = acc[fr][ct2][q] + bv;
            }
        }
    }
}

extern "C" void kernel_launch(void* const* d_in, const int* in_sizes, int n_in,
                              void* d_out, int out_size, void* d_ws, size_t ws_size,
                              hipStream_t stream)
{
    const float* h   = (const float*)d_in[0];
    const int*   src = (const int*)d_in[1];
    const int*   dst = (const int*)d_in[2];
    const float* Wm1 = (const float*)d_in[3];
    const float* bm1 = (const float*)d_in[4];
    const float* Wm2 = (const float*)d_in[5];
    const float* bm2 = (const float*)d_in[6];
    const float* Wm3 = (const float*)d_in[7];
    const float* bm3 = (const float*)d_in[8];
    const float* Wa1 = (const float*)d_in[9];
    const float* ba1 = (const float*)d_in[10];
    const float* Wa2 = (const float*)d_in[11];
    const float* ba2 = (const float*)d_in[12];
    const float* Wa3 = (const float*)d_in[13];
    const float* ba3 = (const float*)d_in[14];
    const float* Wc1 = (const float*)d_in[15];
    const float* bc1 = (const float*)d_in[16];
    const float* Wc2 = (const float*)d_in[17];
    const float* bc2 = (const float*)d_in[18];

    const int N = in_sizes[0] / NDIM;
    const int E = in_sizes[1];
    const int npb = (N + NBKT - 1) / NBKT;
    float* out = (float*)d_out;

    // workspace layout (wt first for 16B alignment)
    unsigned short* wt  = (unsigned short*)d_ws;                 // 6*32768 ushorts
    unsigned short* mb1 = wt + 6 * 32768;                        // N*128 bf16 (hneigh)
    unsigned short* mb2 = mb1 + (size_t)N * NDIM;                // N*128 bf16 (msg)
    float* proj = (float*)(mb2 + (size_t)N * NDIM);              // N*8
    int* offs   = (int*)(proj + (size_t)N * 8);                  // N+1
    int* hist   = offs + N + 1;                                  // NBKT*NWPART
    int* bbase  = hist + NBKT * NWPART;                          // NBKT+1
    int* btot   = bbase + NBKT + 1;                              // NBKT
    unsigned* ebuf = (unsigned*)(btot + NBKT);                   // E
    int* perm   = (int*)(ebuf + E);                              // E

    const unsigned short* wt_m1  = wt;
    const unsigned short* wt_m2  = wt + 1 * 32768;
    const unsigned short* wt_m3  = wt + 2 * 32768;
    const unsigned short* wt_c1a = wt + 3 * 32768;
    const unsigned short* wt_c1b = wt + 4 * 32768;
    const unsigned short* wt_c2  = wt + 5 * 32768;

    k_cvt_w<<<dim3(64, 6), 256, 0, stream>>>(Wm1, Wm2, Wm3, Wc1, Wc1 + 128 * 128, Wc2, wt);
    k_proj<<<(N + 15) / 16, 256, 0, stream>>>(h, Wa1, Wa2, Wa3, proj, N);

    // ---- bucketed CSR build
    k_part1<<<NWPART, 256, 0, stream>>>(dst, hist, E, npb);
    k_pscan_a<<<NBKT, NWPART, 0, stream>>>(hist, btot);
    k_pscan_b<<<1, NBKT, 0, stream>>>(btot, bbase, E);
    k_part2<<<NWPART, 256, 0, stream>>>(src, dst, hist, bbase, ebuf, E, npb);
    k_bucket<<<NBKT, 256, 0, stream>>>(ebuf, bbase, offs, perm, N, npb, E);

    int gb = (N + 63) / 64;
    size_t lds = (32768 + 8192) * sizeof(unsigned short);   // 80 KB
    // fused 3-layer message MLP -> msg (mb2)
    k_mlp3<<<gb, 512, lds, stream>>>(h, wt_m1, wt_m2, wt_m3, bm1, bm2, bm3, mb2, N);

    // aggregation -> hneigh (mb1)
    int nwaves = (N + 3) / 4;
    int nblk   = (nwaves + 3) / 4;
    k_aggr<<<nblk, 256, 0, stream>>>(mb2, proj, offs, perm, ba1, ba2, ba3, mb1, N);

    // fused head -> out
    k_head<<<gb, 512, lds, stream>>>(h, mb1, wt_c1a, wt_c1b, wt_c2, bc1, bc2, out, N);
}